// Round 3
// baseline (665.202 us; speedup 1.0000x reference)
//
#include <hip/hip_runtime.h>
#include <hip/hip_bf16.h>
#include <cstdint>
#include <cstddef>

typedef unsigned short u16;
typedef __attribute__((ext_vector_type(8))) short bf16x8;      // MFMA A/B frag
typedef __attribute__((ext_vector_type(4))) float f32x4;       // MFMA C/D frag
typedef __attribute__((ext_vector_type(8))) unsigned short u16x8;

#define DI __device__ __forceinline__

constexpr int BATCH  = 4096;
constexpr int S1     = 15;
constexpr int DPAD   = 128;   // 120 padded to 128
constexpr int H      = 512;
constexpr int OUTC   = 99;
constexpr int OUTPAD = 112;   // 99 padded to 7*16
constexpr int CHUNK  = 5;     // sites per pass (workspace limit)

DI u16 f2bf(float f) {
  __hip_bfloat16 h = __float2bfloat16(f);
  return __builtin_bit_cast(u16, h);
}
DI float bf2f(u16 u) {
  __hip_bfloat16 h = __builtin_bit_cast(__hip_bfloat16, u);
  return __bfloat162float(h);
}
struct BfPair { u16 hi, lo; };
// split f32 -> hi bf16 + lo bf16 (residual); hi+lo carries ~17 mantissa bits
DI BfPair split2(float v) {
  BfPair r;
  r.hi = f2bf(v);
  r.lo = f2bf(v - bf2f(r.hi));
  return r;
}

// jax.nn.gelu default = tanh approximation
DI float gelu_tanh(float x) {
  float z = 0.7978845608028654f * (x + 0.044715f * x * x * x);
  return 0.5f * x * (1.f + tanhf(z));
}

// ---------------- embeddings: e[b][d] split hi/lo, d in [0,128) --------------
__global__ void embed_kernel(const float* __restrict__ x,
                             u16* __restrict__ eh, u16* __restrict__ el) {
  const int b = blockIdx.x, d = threadIdx.x;  // 128 threads
  float v = 0.f;
  if (d < 120) {
    const float divs[4] = {1.f, 0.31622776601683794f, 0.1f, 0.03162277660168379f};
    int site = d >> 3, j = d & 7;
    float arg = x[b * 16 + site] * divs[j & 3];
    v = (j < 4) ? sinf(arg) : cosf(arg);
  }
  BfPair r = split2(v);
  eh[b * DPAD + d] = r.hi;
  el[b * DPAD + d] = r.lo;
}

// ---- transpose+convert+split: dst{h,l}[s][n][k] = split(src[s][k][n]) -------
__global__ __launch_bounds__(256) void transpose_conv_kernel(
    const float* __restrict__ src, u16* __restrict__ dsth, u16* __restrict__ dstl,
    int K, int N, int Kpad, int Npad, int maskMul) {
  __shared__ float tile[32][33];
  const int s  = blockIdx.z;
  const int kb = blockIdx.x * 32, nb = blockIdx.y * 32;
  const int tx = threadIdx.x & 31, ty = threadIdx.x >> 5;  // 32 x 8
  for (int i = ty; i < 32; i += 8) {
    int k = kb + i, n = nb + tx;
    tile[i][tx] = (k < K && n < N) ? src[((size_t)s * K + k) * N + n] : 0.f;
  }
  __syncthreads();
  const int klim = maskMul ? maskMul * (s + 1) : 0x7FFFFFFF;
  for (int i = ty; i < 32; i += 8) {
    int n = nb + i, k = kb + tx;
    if (n < Npad && k < Kpad) {
      float v = (k < klim) ? tile[tx][i] : 0.f;
      size_t o = ((size_t)s * Npad + n) * Kpad + k;
      BfPair r = split2(v);
      dsth[o] = r.hi;
      dstl[o] = r.lo;
    }
  }
}

// ------------- split-precision bf16 MFMA GEMM -------------------------------
// acc = Ah*Bh + Ah*Bl + Al*Bh  (~f32 accuracy)
// A{h,l}: [M][Kd] per-site stride strideAS (0 = shared); W{h,l}: [site][Npad][Kd]
// epilogue: + bias (+ resid hi+lo); store f32 or split hi/lo
template<int BM, int BN, int BK, int WM, int WN, bool RES, bool F32OUT>
__global__ __launch_bounds__(256) void gemm_kernel(
    const u16* __restrict__ Ah, const u16* __restrict__ Al,
    const u16* __restrict__ Wh, const u16* __restrict__ Wl,
    const float* __restrict__ bias,
    const u16* __restrict__ resH, const u16* __restrict__ resL,
    void* __restrict__ outP, u16* __restrict__ outLo,
    int M, int Kd, int Npad, int Nout, int strideAS) {
  constexpr int LDK = BK + 8;
  __shared__ __align__(16) u16 AsH[BM * LDK];
  __shared__ __align__(16) u16 AsL[BM * LDK];
  __shared__ __align__(16) u16 BsH[BN * LDK];
  __shared__ __align__(16) u16 BsL[BN * LDK];
  const int s  = blockIdx.z;
  const int m0 = blockIdx.x * BM;
  const int n0 = blockIdx.y * BN;
  const u16* aph = Ah + (size_t)s * strideAS;
  const u16* apl = Al + (size_t)s * strideAS;
  const u16* wph = Wh + (size_t)s * Npad * Kd;
  const u16* wpl = Wl + (size_t)s * Npad * Kd;
  const int tid  = threadIdx.x;
  const int wave = tid >> 6, lane = tid & 63;
  constexpr int WGN = BN / WN;
  const int wr = wave / WGN, wc = wave % WGN;
  constexpr int FM = WM / 16, FN = WN / 16;
  f32x4 acc[FM][FN] = {};
  constexpr int CPR = BK / 8;
  const int laneRow = lane & 15;
  const int laneK   = (lane >> 4) * 8;

  for (int k0 = 0; k0 < Kd; k0 += BK) {
    __syncthreads();
    for (int idx = tid; idx < BM * CPR; idx += 256) {
      int r = idx / CPR, c = idx % CPR;
      size_t g = (size_t)(m0 + r) * Kd + k0 + c * 8;
      *reinterpret_cast<u16x8*>(&AsH[r * LDK + c * 8]) = *reinterpret_cast<const u16x8*>(&aph[g]);
      *reinterpret_cast<u16x8*>(&AsL[r * LDK + c * 8]) = *reinterpret_cast<const u16x8*>(&apl[g]);
    }
    for (int idx = tid; idx < BN * CPR; idx += 256) {
      int r = idx / CPR, c = idx % CPR;
      size_t g = (size_t)(n0 + r) * Kd + k0 + c * 8;
      *reinterpret_cast<u16x8*>(&BsH[r * LDK + c * 8]) = *reinterpret_cast<const u16x8*>(&wph[g]);
      *reinterpret_cast<u16x8*>(&BsL[r * LDK + c * 8]) = *reinterpret_cast<const u16x8*>(&wpl[g]);
    }
    __syncthreads();
#pragma unroll
    for (int kk = 0; kk < BK / 32; ++kk) {
      const int kof = kk * 32 + laneK;
      bf16x8 ah[FM], al[FM], bh[FN], bl[FN];
#pragma unroll
      for (int mi = 0; mi < FM; ++mi) {
        const int r = (wr * WM + mi * 16 + laneRow) * LDK + kof;
        ah[mi] = *reinterpret_cast<const bf16x8*>(&AsH[r]);
        al[mi] = *reinterpret_cast<const bf16x8*>(&AsL[r]);
      }
#pragma unroll
      for (int ni = 0; ni < FN; ++ni) {
        const int r = (wc * WN + ni * 16 + laneRow) * LDK + kof;
        bh[ni] = *reinterpret_cast<const bf16x8*>(&BsH[r]);
        bl[ni] = *reinterpret_cast<const bf16x8*>(&BsL[r]);
      }
#pragma unroll
      for (int mi = 0; mi < FM; ++mi)
#pragma unroll
        for (int ni = 0; ni < FN; ++ni) {
          acc[mi][ni] = __builtin_amdgcn_mfma_f32_16x16x32_bf16(ah[mi], bh[ni], acc[mi][ni], 0, 0, 0);
          acc[mi][ni] = __builtin_amdgcn_mfma_f32_16x16x32_bf16(ah[mi], bl[ni], acc[mi][ni], 0, 0, 0);
          acc[mi][ni] = __builtin_amdgcn_mfma_f32_16x16x32_bf16(al[mi], bh[ni], acc[mi][ni], 0, 0, 0);
        }
    }
  }

  const int rbase = (lane >> 4) * 4;
#pragma unroll
  for (int mi = 0; mi < FM; ++mi) {
#pragma unroll
    for (int ni = 0; ni < FN; ++ni) {
#pragma unroll
      for (int r = 0; r < 4; ++r) {
        const int gm = m0 + wr * WM + mi * 16 + rbase + r;
        const int gn = n0 + wc * WN + ni * 16 + laneRow;
        if (gn < Nout) {
          float v = acc[mi][ni][r] + bias[s * Nout + gn];
          const size_t oidx = ((size_t)s * M + gm) * (size_t)Nout + gn;
          if constexpr (RES) {
            const size_t ridx = (size_t)s * strideAS + (size_t)gm * H + gn;
            v += bf2f(resH[ridx]) + bf2f(resL[ridx]);
          }
          if constexpr (F32OUT) {
            reinterpret_cast<float*>(outP)[oidx] = v;
          } else {
            BfPair pr = split2(v);
            reinterpret_cast<u16*>(outP)[oidx] = pr.hi;
            outLo[oidx] = pr.lo;
          }
        }
      }
    }
  }
}

// ------- fused gelu + layernorm, in place on hi/lo pair, one wave per row ----
__global__ __launch_bounds__(256) void gelu_ln_kernel(
    u16* __restrict__ bh, u16* __restrict__ bl,
    const float* __restrict__ lns, const float* __restrict__ lnb) {
  const int row  = blockIdx.x * 4 + (threadIdx.x >> 6);
  const int lane = threadIdx.x & 63;
  const size_t base = (size_t)row * H + lane * 8;
  u16x8 rh = *reinterpret_cast<const u16x8*>(&bh[base]);
  u16x8 rl = *reinterpret_cast<const u16x8*>(&bl[base]);
  float v[8];
  float sum = 0.f, sq = 0.f;
#pragma unroll
  for (int j = 0; j < 8; ++j) {
    float g = gelu_tanh(bf2f(rh[j]) + bf2f(rl[j]));
    v[j] = g; sum += g; sq += g * g;
  }
#pragma unroll
  for (int o = 32; o > 0; o >>= 1) {
    sum += __shfl_xor(sum, o, 64);
    sq  += __shfl_xor(sq, o, 64);
  }
  const float mean = sum * (1.f / 512.f);
  const float var  = sq * (1.f / 512.f) - mean * mean;
  const float rstd = 1.f / sqrtf(var + 1e-6f);
  const int site = row / BATCH;   // local site within chunk (lns pre-offset)
  const float* sp = lns + site * H + lane * 8;
  const float* bp = lnb + site * H + lane * 8;
  u16x8 oh, ol;
#pragma unroll
  for (int j = 0; j < 8; ++j) {
    float z = (v[j] - mean) * rstd * sp[j] + bp[j];
    BfPair pr = split2(z);
    oh[j] = pr.hi;
    ol[j] = pr.lo;
  }
  *reinterpret_cast<u16x8*>(&bh[base]) = oh;
  *reinterpret_cast<u16x8*>(&bl[base]) = ol;
}

// ---------------- RQS spline: one thread per (b,i), params via LDS -----------
DI float invsymlu(float u) { return u >= 0.f ? u + 1.f : 1.f / (1.f - u); }

__global__ __launch_bounds__(128) void spline_kernel(
    const float* __restrict__ x, const float* __restrict__ bias0,
    const float* __restrict__ p, float* __restrict__ out0, float* __restrict__ ladbuf) {
  __shared__ float prm[128 * 101];   // stride 101: conflict-free
  const int i  = blockIdx.x;         // 0..15
  const int b0 = blockIdx.y * 128;
  if (i == 0) {
    for (int idx = threadIdx.x; idx < 128 * OUTC; idx += 128)
      prm[(idx / OUTC) * 101 + idx % OUTC] = bias0[idx % OUTC];
  } else {
    const float* src = p + ((size_t)(i - 1) * BATCH + b0) * OUTC;
    for (int idx = threadIdx.x; idx < 128 * OUTC; idx += 128)
      prm[(idx / OUTC) * 101 + idx % OUTC] = src[idx];
  }
  __syncthreads();
  const float* P = &prm[threadIdx.x * 101];
  const int b = b0 + threadIdx.x;
  const float inp = x[b * 16 + i];

  float tw = 0.f, th = 0.f;
  for (int k = 0; k < 32; ++k) tw += 0.001f + invsymlu(P[k]);
  for (int k = 0; k < 32; ++k) th += 0.001f + invsymlu(P[32 + k]);
  const float cx = P[97], cy = P[98];
  const float w0 = cx - 0.5f * tw, wK = cx + 0.5f * tw;
  const float h0 = cy - 0.5f * th, hK = cy + 0.5f * th;
  const float d0 = 0.001f + invsymlu(P[64]);
  const float dK = 0.001f + invsymlu(P[96]);
  float outv, lad;
  if (inp < w0) {
    outv = h0 - (w0 - inp) * d0;
    lad  = logf(d0);
  } else if (inp >= wK) {
    outv = (inp - wK) * dK + hK;
    lad  = logf(dK);
  } else {
    float run = w0, icw = w0, ibw = 1.f;
    int bin = 0;
    for (int k = 0; k < 32; ++k) {
      float wk = 0.001f + invsymlu(P[k]);
      if (inp >= run) { bin = k; icw = run; ibw = wk; }
      run += wk;
    }
    float runh = h0;
    for (int k = 0; k < bin; ++k) runh += 0.001f + invsymlu(P[32 + k]);
    const float ih    = 0.001f + invsymlu(P[32 + bin]);
    const float ich   = runh;
    const float ider  = 0.001f + invsymlu(P[64 + bin]);
    const float iderp = 0.001f + invsymlu(P[64 + bin + 1]);
    const float idl   = ih / ibw;
    const float theta = (inp - icw) / ibw;
    const float omt   = 1.f - theta;
    const float tomt  = theta * omt;
    const float num   = ih * (idl * theta * theta + ider * tomt);
    const float den   = idl + (ider + iderp - 2.f * idl) * tomt;
    outv = ich + num / den;
    const float dnum = idl * idl * (iderp * theta * theta + 2.f * idl * tomt + ider * omt * omt);
    lad = logf(dnum) - 2.f * logf(den);
  }
  out0[b * 16 + i]   = outv;
  ladbuf[b * 16 + i] = lad;
}

__global__ void lad_reduce_kernel(const float* __restrict__ ladbuf, float* __restrict__ out1) {
  const int b = blockIdx.x * 256 + threadIdx.x;
  float s = 0.f;
#pragma unroll
  for (int i = 0; i < 16; ++i) s += ladbuf[b * 16 + i];
  out1[b] = s;
}

// ---------------------------------------------------------------------------
extern "C" void kernel_launch(void* const* d_in, const int* in_sizes, int n_in,
                              void* d_out, int out_size, void* d_ws, size_t ws_size,
                              hipStream_t stream) {
  const float* x     = (const float*)d_in[0];
  const float* bias0 = (const float*)d_in[1];
  const float* W0    = (const float*)d_in[2];
  const float* b0    = (const float*)d_in[3];
  const float* ln0s  = (const float*)d_in[4];
  const float* ln0b  = (const float*)d_in[5];
  const float* W1    = (const float*)d_in[6];
  const float* b1    = (const float*)d_in[7];
  const float* ln1s  = (const float*)d_in[8];
  const float* ln1b  = (const float*)d_in[9];
  const float* W2    = (const float*)d_in[10];
  const float* b2    = (const float*)d_in[11];
  const float* ln2s  = (const float*)d_in[12];
  const float* ln2b  = (const float*)d_in[13];
  const float* Wf    = (const float*)d_in[14];
  const float* bfb   = (const float*)d_in[15];
  float* out0 = (float*)d_out;
  float* out1 = out0 + BATCH * 16;

  char* ws = (char*)d_ws;
  size_t off = 0;
  auto take = [&](size_t bytes) {
    char* q = ws + off;
    off += (bytes + 255) & ~(size_t)255;
    return q;
  };
  u16* eh   = (u16*)take((size_t)BATCH * DPAD * 2);
  u16* el   = (u16*)take((size_t)BATCH * DPAD * 2);
  u16* W0Th = (u16*)take((size_t)S1 * H * DPAD * 2);
  u16* W0Tl = (u16*)take((size_t)S1 * H * DPAD * 2);
  u16* W1Th = (u16*)take((size_t)S1 * H * H * 2);
  u16* W1Tl = (u16*)take((size_t)S1 * H * H * 2);
  u16* W2Th = (u16*)take((size_t)S1 * H * H * 2);
  u16* W2Tl = (u16*)take((size_t)S1 * H * H * 2);
  u16* WfTh = (u16*)take((size_t)S1 * OUTPAD * H * 2);
  u16* WfTl = (u16*)take((size_t)S1 * OUTPAD * H * 2);
  u16* P1h  = (u16*)take((size_t)CHUNK * BATCH * H * 2);
  u16* P1l  = (u16*)take((size_t)CHUNK * BATCH * H * 2);
  u16* P2h  = (u16*)take((size_t)CHUNK * BATCH * H * 2);
  u16* P2l  = (u16*)take((size_t)CHUNK * BATCH * H * 2);
  float* pbuf = (float*)take((size_t)S1 * BATCH * OUTC * 4);
  float* ladb = (float*)take((size_t)BATCH * 16 * 4);

  embed_kernel<<<BATCH, 128, 0, stream>>>(x, eh, el);
  transpose_conv_kernel<<<dim3(4, 16, S1), 256, 0, stream>>>(W0, W0Th, W0Tl, 120, H, DPAD, H, 8);
  transpose_conv_kernel<<<dim3(16, 16, S1), 256, 0, stream>>>(W1, W1Th, W1Tl, H, H, H, H, 0);
  transpose_conv_kernel<<<dim3(16, 16, S1), 256, 0, stream>>>(W2, W2Th, W2Tl, H, H, H, H, 0);
  transpose_conv_kernel<<<dim3(16, 4, S1), 256, 0, stream>>>(Wf, WfTh, WfTl, H, OUTC, H, OUTPAD, 0);

  for (int c = 0; c < S1 / CHUNK; ++c) {
    const int sb = c * CHUNK;
    // layer 0: e (shared) -> P2
    gemm_kernel<128, 128, 32, 64, 64, false, false><<<dim3(32, 4, CHUNK), 256, 0, stream>>>(
        eh, el, W0Th + (size_t)sb * H * DPAD, W0Tl + (size_t)sb * H * DPAD,
        b0 + sb * H, nullptr, nullptr, P2h, P2l, BATCH, DPAD, H, H, 0);
    gelu_ln_kernel<<<CHUNK * BATCH / 4, 256, 0, stream>>>(P2h, P2l, ln0s + sb * H, ln0b + sb * H);
    // layer 1: P2 -> P1 (residual P2)
    gemm_kernel<128, 128, 32, 64, 64, true, false><<<dim3(32, 4, CHUNK), 256, 0, stream>>>(
        P2h, P2l, W1Th + (size_t)sb * H * H, W1Tl + (size_t)sb * H * H,
        b1 + sb * H, P2h, P2l, P1h, P1l, BATCH, H, H, H, BATCH * H);
    gelu_ln_kernel<<<CHUNK * BATCH / 4, 256, 0, stream>>>(P1h, P1l, ln1s + sb * H, ln1b + sb * H);
    // layer 2: P1 -> P2 (residual P1)
    gemm_kernel<128, 128, 32, 64, 64, true, false><<<dim3(32, 4, CHUNK), 256, 0, stream>>>(
        P1h, P1l, W2Th + (size_t)sb * H * H, W2Tl + (size_t)sb * H * H,
        b2 + sb * H, P1h, P1l, P2h, P2l, BATCH, H, H, H, BATCH * H);
    gelu_ln_kernel<<<CHUNK * BATCH / 4, 256, 0, stream>>>(P2h, P2l, ln2s + sb * H, ln2b + sb * H);
    // final projection: P2 -> pbuf (f32)
    gemm_kernel<128, 112, 32, 32, 112, false, true><<<dim3(32, 1, CHUNK), 256, 0, stream>>>(
        P2h, P2l, WfTh + (size_t)sb * OUTPAD * H, WfTl + (size_t)sb * OUTPAD * H,
        bfb + sb * OUTC, nullptr, nullptr, pbuf + (size_t)sb * BATCH * OUTC, nullptr,
        BATCH, H, OUTPAD, OUTC, BATCH * H);
  }

  spline_kernel<<<dim3(16, 32), 128, 0, stream>>>(x, bias0, pbuf, out0, ladb);
  lad_reduce_kernel<<<BATCH / 256, 256, 0, stream>>>(ladb, out1);
}

// Round 4
// 664.154 us; speedup vs baseline: 1.0016x; 1.0016x over previous
//
#include <hip/hip_runtime.h>
#include <hip/hip_bf16.h>
#include <cstdint>
#include <cstddef>

typedef unsigned short u16;
typedef __attribute__((ext_vector_type(8))) short bf16x8;      // MFMA A/B frag
typedef __attribute__((ext_vector_type(4))) float f32x4;       // MFMA C/D frag
typedef __attribute__((ext_vector_type(8))) unsigned short u16x8;

#define DI __device__ __forceinline__

constexpr int BATCH  = 4096;
constexpr int S1     = 15;
constexpr int DPAD   = 128;   // 120 padded to 128
constexpr int H      = 512;
constexpr int OUTC   = 99;
constexpr int OUTPAD = 112;   // 99 padded to 7*16

DI u16 f2bf(float f) {
  __hip_bfloat16 h = __float2bfloat16(f);
  return __builtin_bit_cast(u16, h);
}
DI float bf2f(u16 u) {
  __hip_bfloat16 h = __builtin_bit_cast(__hip_bfloat16, u);
  return __bfloat162float(h);
}
struct BfPair { u16 hi, lo; };
// split f32 -> hi bf16 + lo bf16 (residual); hi+lo carries ~17 mantissa bits
DI BfPair split2(float v) {
  BfPair r;
  r.hi = f2bf(v);
  r.lo = f2bf(v - bf2f(r.hi));
  return r;
}

// jax.nn.gelu default = tanh approximation
DI float gelu_tanh(float x) {
  float z = 0.7978845608028654f * (x + 0.044715f * x * x * x);
  return 0.5f * x * (1.f + tanhf(z));
}

// ---------------- embeddings: e[b][d] split hi/lo, d in [0,128) --------------
__global__ void embed_kernel(const float* __restrict__ x,
                             u16* __restrict__ eh, u16* __restrict__ el) {
  const int b = blockIdx.x, d = threadIdx.x;  // 128 threads
  float v = 0.f;
  if (d < 120) {
    const float divs[4] = {1.f, 0.31622776601683794f, 0.1f, 0.03162277660168379f};
    int site = d >> 3, j = d & 7;
    float arg = x[b * 16 + site] * divs[j & 3];
    v = (j < 4) ? sinf(arg) : cosf(arg);
  }
  BfPair r = split2(v);
  eh[b * DPAD + d] = r.hi;
  el[b * DPAD + d] = r.lo;
}

// ---- transpose+convert+split: dst{h,l}[s][n][k] = split(src[s][k][n]) -------
__global__ __launch_bounds__(256) void transpose_conv_kernel(
    const float* __restrict__ src, u16* __restrict__ dsth, u16* __restrict__ dstl,
    int K, int N, int Kpad, int Npad, int maskMul) {
  __shared__ float tile[32][33];
  const int s  = blockIdx.z;
  const int kb = blockIdx.x * 32, nb = blockIdx.y * 32;
  const int tx = threadIdx.x & 31, ty = threadIdx.x >> 5;  // 32 x 8
  for (int i = ty; i < 32; i += 8) {
    int k = kb + i, n = nb + tx;
    tile[i][tx] = (k < K && n < N) ? src[((size_t)s * K + k) * N + n] : 0.f;
  }
  __syncthreads();
  const int klim = maskMul ? maskMul * (s + 1) : 0x7FFFFFFF;
  for (int i = ty; i < 32; i += 8) {
    int n = nb + i, k = kb + tx;
    if (n < Npad && k < Kpad) {
      float v = (k < klim) ? tile[tx][i] : 0.f;
      size_t o = ((size_t)s * Npad + n) * Kpad + k;
      BfPair r = split2(v);
      dsth[o] = r.hi;
      dstl[o] = r.lo;
    }
  }
}

// ------------- split-precision bf16 MFMA GEMM -------------------------------
// acc = Ah*Bh + Ah*Bl + Al*Bh  (~f32 accuracy)
// A{h,l}: [M][Kd] per-site stride strideAS (0 = shared); W{h,l}: [site][Npad][Kd]
// epilogue: + bias (+ resid hi+lo); store f32 or split hi/lo
template<int BM, int BN, int BK, int WM, int WN, bool RES, bool F32OUT>
__global__ __launch_bounds__(256) void gemm_kernel(
    const u16* __restrict__ Ah, const u16* __restrict__ Al,
    const u16* __restrict__ Wh, const u16* __restrict__ Wl,
    const float* __restrict__ bias,
    const u16* __restrict__ resH, const u16* __restrict__ resL,
    void* __restrict__ outP, u16* __restrict__ outLo,
    int M, int Kd, int Npad, int Nout, int strideAS) {
  constexpr int LDK = BK + 8;
  __shared__ __align__(16) u16 AsH[BM * LDK];
  __shared__ __align__(16) u16 AsL[BM * LDK];
  __shared__ __align__(16) u16 BsH[BN * LDK];
  __shared__ __align__(16) u16 BsL[BN * LDK];
  const int s  = blockIdx.z;
  const int m0 = blockIdx.x * BM;
  const int n0 = blockIdx.y * BN;
  const u16* aph = Ah + (size_t)s * strideAS;
  const u16* apl = Al + (size_t)s * strideAS;
  const u16* wph = Wh + (size_t)s * Npad * Kd;
  const u16* wpl = Wl + (size_t)s * Npad * Kd;
  const int tid  = threadIdx.x;
  const int wave = tid >> 6, lane = tid & 63;
  constexpr int WGN = BN / WN;
  const int wr = wave / WGN, wc = wave % WGN;
  constexpr int FM = WM / 16, FN = WN / 16;
  f32x4 acc[FM][FN] = {};
  constexpr int CPR = BK / 8;
  const int laneRow = lane & 15;
  const int laneK   = (lane >> 4) * 8;

  for (int k0 = 0; k0 < Kd; k0 += BK) {
    __syncthreads();
    for (int idx = tid; idx < BM * CPR; idx += 256) {
      int r = idx / CPR, c = idx % CPR;
      size_t g = (size_t)(m0 + r) * Kd + k0 + c * 8;
      *reinterpret_cast<u16x8*>(&AsH[r * LDK + c * 8]) = *reinterpret_cast<const u16x8*>(&aph[g]);
      *reinterpret_cast<u16x8*>(&AsL[r * LDK + c * 8]) = *reinterpret_cast<const u16x8*>(&apl[g]);
    }
    for (int idx = tid; idx < BN * CPR; idx += 256) {
      int r = idx / CPR, c = idx % CPR;
      size_t g = (size_t)(n0 + r) * Kd + k0 + c * 8;
      *reinterpret_cast<u16x8*>(&BsH[r * LDK + c * 8]) = *reinterpret_cast<const u16x8*>(&wph[g]);
      *reinterpret_cast<u16x8*>(&BsL[r * LDK + c * 8]) = *reinterpret_cast<const u16x8*>(&wpl[g]);
    }
    __syncthreads();
#pragma unroll
    for (int kk = 0; kk < BK / 32; ++kk) {
      const int kof = kk * 32 + laneK;
      bf16x8 ah[FM], al[FM], bh[FN], bl[FN];
#pragma unroll
      for (int mi = 0; mi < FM; ++mi) {
        const int r = (wr * WM + mi * 16 + laneRow) * LDK + kof;
        ah[mi] = *reinterpret_cast<const bf16x8*>(&AsH[r]);
        al[mi] = *reinterpret_cast<const bf16x8*>(&AsL[r]);
      }
#pragma unroll
      for (int ni = 0; ni < FN; ++ni) {
        const int r = (wc * WN + ni * 16 + laneRow) * LDK + kof;
        bh[ni] = *reinterpret_cast<const bf16x8*>(&BsH[r]);
        bl[ni] = *reinterpret_cast<const bf16x8*>(&BsL[r]);
      }
#pragma unroll
      for (int mi = 0; mi < FM; ++mi)
#pragma unroll
        for (int ni = 0; ni < FN; ++ni) {
          acc[mi][ni] = __builtin_amdgcn_mfma_f32_16x16x32_bf16(ah[mi], bh[ni], acc[mi][ni], 0, 0, 0);
          acc[mi][ni] = __builtin_amdgcn_mfma_f32_16x16x32_bf16(ah[mi], bl[ni], acc[mi][ni], 0, 0, 0);
          acc[mi][ni] = __builtin_amdgcn_mfma_f32_16x16x32_bf16(al[mi], bh[ni], acc[mi][ni], 0, 0, 0);
        }
    }
  }

  const int rbase = (lane >> 4) * 4;
#pragma unroll
  for (int mi = 0; mi < FM; ++mi) {
#pragma unroll
    for (int ni = 0; ni < FN; ++ni) {
#pragma unroll
      for (int r = 0; r < 4; ++r) {
        const int gm = m0 + wr * WM + mi * 16 + rbase + r;
        const int gn = n0 + wc * WN + ni * 16 + laneRow;
        if (gn < Nout) {
          float v = acc[mi][ni][r] + bias[s * Nout + gn];
          const size_t oidx = ((size_t)s * M + gm) * (size_t)Nout + gn;
          if constexpr (RES) {
            const size_t ridx = (size_t)s * strideAS + (size_t)gm * H + gn;
            v += bf2f(resH[ridx]) + bf2f(resL[ridx]);
          }
          if constexpr (F32OUT) {
            reinterpret_cast<float*>(outP)[oidx] = v;
          } else {
            BfPair pr = split2(v);
            reinterpret_cast<u16*>(outP)[oidx] = pr.hi;
            outLo[oidx] = pr.lo;
          }
        }
      }
    }
  }
}

// ------- fused gelu + layernorm, in place on hi/lo pair, one wave per row ----
__global__ __launch_bounds__(256) void gelu_ln_kernel(
    u16* __restrict__ bh, u16* __restrict__ bl,
    const float* __restrict__ lns, const float* __restrict__ lnb) {
  const int row  = blockIdx.x * 4 + (threadIdx.x >> 6);
  const int lane = threadIdx.x & 63;
  const size_t base = (size_t)row * H + lane * 8;
  u16x8 rh = *reinterpret_cast<const u16x8*>(&bh[base]);
  u16x8 rl = *reinterpret_cast<const u16x8*>(&bl[base]);
  float v[8];
  float sum = 0.f, sq = 0.f;
#pragma unroll
  for (int j = 0; j < 8; ++j) {
    float g = gelu_tanh(bf2f(rh[j]) + bf2f(rl[j]));
    v[j] = g; sum += g; sq += g * g;
  }
#pragma unroll
  for (int o = 32; o > 0; o >>= 1) {
    sum += __shfl_xor(sum, o, 64);
    sq  += __shfl_xor(sq, o, 64);
  }
  const float mean = sum * (1.f / 512.f);
  const float var  = sq * (1.f / 512.f) - mean * mean;
  const float rstd = 1.f / sqrtf(var + 1e-6f);
  const int site = row / BATCH;   // site index (lns is site-base pointer)
  const float* sp = lns + site * H + lane * 8;
  const float* bp = lnb + site * H + lane * 8;
  u16x8 oh, ol;
#pragma unroll
  for (int j = 0; j < 8; ++j) {
    float z = (v[j] - mean) * rstd * sp[j] + bp[j];
    BfPair pr = split2(z);
    oh[j] = pr.hi;
    ol[j] = pr.lo;
  }
  *reinterpret_cast<u16x8*>(&bh[base]) = oh;
  *reinterpret_cast<u16x8*>(&bl[base]) = ol;
}

// ---------------- RQS spline: one thread per (b,i), params via LDS -----------
DI float invsymlu(float u) { return u >= 0.f ? u + 1.f : 1.f / (1.f - u); }

__global__ __launch_bounds__(128) void spline_kernel(
    const float* __restrict__ x, const float* __restrict__ bias0,
    const float* __restrict__ p, float* __restrict__ out0, float* __restrict__ ladbuf) {
  __shared__ float prm[128 * 101];   // stride 101: conflict-free
  const int i  = blockIdx.x;         // 0..15
  const int b0 = blockIdx.y * 128;
  if (i == 0) {
    for (int idx = threadIdx.x; idx < 128 * OUTC; idx += 128)
      prm[(idx / OUTC) * 101 + idx % OUTC] = bias0[idx % OUTC];
  } else {
    const float* src = p + ((size_t)(i - 1) * BATCH + b0) * OUTC;
    for (int idx = threadIdx.x; idx < 128 * OUTC; idx += 128)
      prm[(idx / OUTC) * 101 + idx % OUTC] = src[idx];
  }
  __syncthreads();
  const float* P = &prm[threadIdx.x * 101];
  const int b = b0 + threadIdx.x;
  const float inp = x[b * 16 + i];

  float tw = 0.f, th = 0.f;
  for (int k = 0; k < 32; ++k) tw += 0.001f + invsymlu(P[k]);
  for (int k = 0; k < 32; ++k) th += 0.001f + invsymlu(P[32 + k]);
  const float cx = P[97], cy = P[98];
  const float w0 = cx - 0.5f * tw, wK = cx + 0.5f * tw;
  const float h0 = cy - 0.5f * th, hK = cy + 0.5f * th;
  const float d0 = 0.001f + invsymlu(P[64]);
  const float dK = 0.001f + invsymlu(P[96]);
  float outv, lad;
  if (inp < w0) {
    outv = h0 - (w0 - inp) * d0;
    lad  = logf(d0);
  } else if (inp >= wK) {
    outv = (inp - wK) * dK + hK;
    lad  = logf(dK);
  } else {
    float run = w0, icw = w0, ibw = 1.f;
    int bin = 0;
    for (int k = 0; k < 32; ++k) {
      float wk = 0.001f + invsymlu(P[k]);
      if (inp >= run) { bin = k; icw = run; ibw = wk; }
      run += wk;
    }
    float runh = h0;
    for (int k = 0; k < bin; ++k) runh += 0.001f + invsymlu(P[32 + k]);
    const float ih    = 0.001f + invsymlu(P[32 + bin]);
    const float ich   = runh;
    const float ider  = 0.001f + invsymlu(P[64 + bin]);
    const float iderp = 0.001f + invsymlu(P[64 + bin + 1]);
    const float idl   = ih / ibw;
    const float theta = (inp - icw) / ibw;
    const float omt   = 1.f - theta;
    const float tomt  = theta * omt;
    const float num   = ih * (idl * theta * theta + ider * tomt);
    const float den   = idl + (ider + iderp - 2.f * idl) * tomt;
    outv = ich + num / den;
    const float dnum = idl * idl * (iderp * theta * theta + 2.f * idl * tomt + ider * omt * omt);
    lad = logf(dnum) - 2.f * logf(den);
  }
  out0[b * 16 + i]   = outv;
  ladbuf[b * 16 + i] = lad;
}

__global__ void lad_reduce_kernel(const float* __restrict__ ladbuf, float* __restrict__ out1) {
  const int b = blockIdx.x * 256 + threadIdx.x;
  float s = 0.f;
#pragma unroll
  for (int i = 0; i < 16; ++i) s += ladbuf[b * 16 + i];
  out1[b] = s;
}

// ---------------------------------------------------------------------------
extern "C" void kernel_launch(void* const* d_in, const int* in_sizes, int n_in,
                              void* d_out, int out_size, void* d_ws, size_t ws_size,
                              hipStream_t stream) {
  const float* x     = (const float*)d_in[0];
  const float* bias0 = (const float*)d_in[1];
  const float* W0    = (const float*)d_in[2];
  const float* b0    = (const float*)d_in[3];
  const float* ln0s  = (const float*)d_in[4];
  const float* ln0b  = (const float*)d_in[5];
  const float* W1    = (const float*)d_in[6];
  const float* b1    = (const float*)d_in[7];
  const float* ln1s  = (const float*)d_in[8];
  const float* ln1b  = (const float*)d_in[9];
  const float* W2    = (const float*)d_in[10];
  const float* b2    = (const float*)d_in[11];
  const float* ln2s  = (const float*)d_in[12];
  const float* ln2b  = (const float*)d_in[13];
  const float* Wf    = (const float*)d_in[14];
  const float* bfb   = (const float*)d_in[15];
  float* out0 = (float*)d_out;
  float* out1 = out0 + BATCH * 16;

  // ---- workspace budget: pick sites-per-pass (15 if it fits, else 5) -------
  const size_t fixedBytes =
      2 * ((size_t)BATCH * DPAD * 2) +          // eh, el
      2 * ((size_t)S1 * H * DPAD * 2) +         // W0T h,l
      4 * ((size_t)S1 * H * H * 2) +            // W1T, W2T h,l
      2 * ((size_t)S1 * OUTPAD * H * 2) +       // WfT h,l
      (size_t)S1 * BATCH * OUTC * 4 +           // pbuf
      (size_t)BATCH * 16 * 4 +                  // ladb
      64 * 256;                                  // alignment slack
  const size_t perSiteP = 4 * ((size_t)BATCH * H * 2);  // P1/P2 h,l per site
  const int CH = (fixedBytes + perSiteP * S1 <= ws_size) ? S1 : 5;

  char* ws = (char*)d_ws;
  size_t off = 0;
  auto take = [&](size_t bytes) {
    char* q = ws + off;
    off += (bytes + 255) & ~(size_t)255;
    return q;
  };
  u16* eh   = (u16*)take((size_t)BATCH * DPAD * 2);
  u16* el   = (u16*)take((size_t)BATCH * DPAD * 2);
  u16* W0Th = (u16*)take((size_t)S1 * H * DPAD * 2);
  u16* W0Tl = (u16*)take((size_t)S1 * H * DPAD * 2);
  u16* W1Th = (u16*)take((size_t)S1 * H * H * 2);
  u16* W1Tl = (u16*)take((size_t)S1 * H * H * 2);
  u16* W2Th = (u16*)take((size_t)S1 * H * H * 2);
  u16* W2Tl = (u16*)take((size_t)S1 * H * H * 2);
  u16* WfTh = (u16*)take((size_t)S1 * OUTPAD * H * 2);
  u16* WfTl = (u16*)take((size_t)S1 * OUTPAD * H * 2);
  u16* P1h  = (u16*)take((size_t)CH * BATCH * H * 2);
  u16* P1l  = (u16*)take((size_t)CH * BATCH * H * 2);
  u16* P2h  = (u16*)take((size_t)CH * BATCH * H * 2);
  u16* P2l  = (u16*)take((size_t)CH * BATCH * H * 2);
  float* pbuf = (float*)take((size_t)S1 * BATCH * OUTC * 4);
  float* ladb = (float*)take((size_t)BATCH * 16 * 4);

  embed_kernel<<<BATCH, 128, 0, stream>>>(x, eh, el);
  transpose_conv_kernel<<<dim3(4, 16, S1), 256, 0, stream>>>(W0, W0Th, W0Tl, 120, H, DPAD, H, 8);
  transpose_conv_kernel<<<dim3(16, 16, S1), 256, 0, stream>>>(W1, W1Th, W1Tl, H, H, H, H, 0);
  transpose_conv_kernel<<<dim3(16, 16, S1), 256, 0, stream>>>(W2, W2Th, W2Tl, H, H, H, H, 0);
  transpose_conv_kernel<<<dim3(16, 4, S1), 256, 0, stream>>>(Wf, WfTh, WfTl, H, OUTC, H, OUTPAD, 0);

  for (int sb = 0; sb < S1; sb += CH) {
    const int nz = (sb + CH <= S1) ? CH : (S1 - sb);
    // layer 0: e (shared) -> P2
    gemm_kernel<128, 128, 32, 64, 64, false, false><<<dim3(32, 4, nz), 256, 0, stream>>>(
        eh, el, W0Th + (size_t)sb * H * DPAD, W0Tl + (size_t)sb * H * DPAD,
        b0 + sb * H, nullptr, nullptr, P2h, P2l, BATCH, DPAD, H, H, 0);
    gelu_ln_kernel<<<nz * BATCH / 4, 256, 0, stream>>>(P2h, P2l, ln0s + sb * H, ln0b + sb * H);
    // layer 1: P2 -> P1 (residual P2)
    gemm_kernel<128, 128, 32, 64, 64, true, false><<<dim3(32, 4, nz), 256, 0, stream>>>(
        P2h, P2l, W1Th + (size_t)sb * H * H, W1Tl + (size_t)sb * H * H,
        b1 + sb * H, P2h, P2l, P1h, P1l, BATCH, H, H, H, BATCH * H);
    gelu_ln_kernel<<<nz * BATCH / 4, 256, 0, stream>>>(P1h, P1l, ln1s + sb * H, ln1b + sb * H);
    // layer 2: P1 -> P2 (residual P1)
    gemm_kernel<128, 128, 32, 64, 64, true, false><<<dim3(32, 4, nz), 256, 0, stream>>>(
        P1h, P1l, W2Th + (size_t)sb * H * H, W2Tl + (size_t)sb * H * H,
        b2 + sb * H, P1h, P1l, P2h, P2l, BATCH, H, H, H, BATCH * H);
    gelu_ln_kernel<<<nz * BATCH / 4, 256, 0, stream>>>(P2h, P2l, ln2s + sb * H, ln2b + sb * H);
    // final projection: P2 -> pbuf (f32)
    gemm_kernel<128, 112, 32, 32, 112, false, true><<<dim3(32, 1, nz), 256, 0, stream>>>(
        P2h, P2l, WfTh + (size_t)sb * OUTPAD * H, WfTl + (size_t)sb * OUTPAD * H,
        bfb + sb * OUTC, nullptr, nullptr, pbuf + (size_t)sb * BATCH * OUTC, nullptr,
        BATCH, H, OUTPAD, OUTC, BATCH * H);
  }

  spline_kernel<<<dim3(16, 32), 128, 0, stream>>>(x, bias0, pbuf, out0, ladb);
  lad_reduce_kernel<<<BATCH / 256, 256, 0, stream>>>(ladb, out1);
}

// Round 5
// 645.190 us; speedup vs baseline: 1.0310x; 1.0294x over previous
//
#include <hip/hip_runtime.h>
#include <hip/hip_bf16.h>
#include <cstdint>
#include <cstddef>

typedef unsigned short u16;
typedef __attribute__((ext_vector_type(8))) short bf16x8;      // MFMA A/B frag
typedef __attribute__((ext_vector_type(4))) float f32x4;       // MFMA C/D frag
typedef __attribute__((ext_vector_type(8))) unsigned short u16x8;

#define DI __device__ __forceinline__

constexpr int BATCH  = 4096;
constexpr int S1     = 15;
constexpr int DPAD   = 128;   // 120 padded to 128
constexpr int H      = 512;
constexpr int OUTC   = 99;
constexpr int OUTPAD = 112;   // 99 padded to 7*16

DI u16 f2bf(float f) {
  __hip_bfloat16 h = __float2bfloat16(f);
  return __builtin_bit_cast(u16, h);
}
DI float bf2f(u16 u) {
  __hip_bfloat16 h = __builtin_bit_cast(__hip_bfloat16, u);
  return __bfloat162float(h);
}
struct BfPair { u16 hi, lo; };
// split f32 -> hi bf16 + lo bf16 (residual); hi+lo carries ~17 mantissa bits
DI BfPair split2(float v) {
  BfPair r;
  r.hi = f2bf(v);
  r.lo = f2bf(v - bf2f(r.hi));
  return r;
}

// jax.nn.gelu default = tanh approximation
DI float gelu_tanh(float x) {
  float z = 0.7978845608028654f * (x + 0.044715f * x * x * x);
  return 0.5f * x * (1.f + tanhf(z));
}

// ---------------- embeddings: e[b][d] split hi/lo, d in [0,128) --------------
__global__ void embed_kernel(const float* __restrict__ x,
                             u16* __restrict__ eh, u16* __restrict__ el) {
  const int b = blockIdx.x, d = threadIdx.x;  // 128 threads
  float v = 0.f;
  if (d < 120) {
    const float divs[4] = {1.f, 0.31622776601683794f, 0.1f, 0.03162277660168379f};
    int site = d >> 3, j = d & 7;
    float arg = x[b * 16 + site] * divs[j & 3];
    v = (j < 4) ? sinf(arg) : cosf(arg);
  }
  BfPair r = split2(v);
  eh[b * DPAD + d] = r.hi;
  el[b * DPAD + d] = r.lo;
}

// ---- transpose+convert+split: dst{h,l}[s][n][k] = split(src[s][k][n]) -------
__global__ __launch_bounds__(256) void transpose_conv_kernel(
    const float* __restrict__ src, u16* __restrict__ dsth, u16* __restrict__ dstl,
    int K, int N, int Kpad, int Npad, int maskMul) {
  __shared__ float tile[32][33];
  const int s  = blockIdx.z;
  const int kb = blockIdx.x * 32, nb = blockIdx.y * 32;
  const int tx = threadIdx.x & 31, ty = threadIdx.x >> 5;  // 32 x 8
  for (int i = ty; i < 32; i += 8) {
    int k = kb + i, n = nb + tx;
    tile[i][tx] = (k < K && n < N) ? src[((size_t)s * K + k) * N + n] : 0.f;
  }
  __syncthreads();
  const int klim = maskMul ? maskMul * (s + 1) : 0x7FFFFFFF;
  for (int i = ty; i < 32; i += 8) {
    int n = nb + i, k = kb + tx;
    if (n < Npad && k < Kpad) {
      float v = (k < klim) ? tile[tx][i] : 0.f;
      size_t o = ((size_t)s * Npad + n) * Kpad + k;
      BfPair r = split2(v);
      dsth[o] = r.hi;
      dstl[o] = r.lo;
    }
  }
}

// ------------- split-precision bf16 MFMA GEMM -------------------------------
// acc = Ah*Bh + Ah*Bl + Al*Bh  (~f32 accuracy)
// A{h,l}: [M][Kd] per-site stride strideAS (0 = shared); W{h,l}: [site][Npad][Kd]
// epilogue: + bias (+ resid hi+lo); store f32 or split hi/lo
template<int BM, int BN, int BK, int WM, int WN, bool RES, bool F32OUT>
__global__ __launch_bounds__(256) void gemm_kernel(
    const u16* __restrict__ Ah, const u16* __restrict__ Al,
    const u16* __restrict__ Wh, const u16* __restrict__ Wl,
    const float* __restrict__ bias,
    const u16* __restrict__ resH, const u16* __restrict__ resL,
    void* __restrict__ outP, u16* __restrict__ outLo,
    int M, int Kd, int Npad, int Nout, int strideAS) {
  constexpr int LDK = BK + 8;
  __shared__ __align__(16) u16 AsH[BM * LDK];
  __shared__ __align__(16) u16 AsL[BM * LDK];
  __shared__ __align__(16) u16 BsH[BN * LDK];
  __shared__ __align__(16) u16 BsL[BN * LDK];
  const int s  = blockIdx.z;
  const int m0 = blockIdx.x * BM;
  const int n0 = blockIdx.y * BN;
  const u16* aph = Ah + (size_t)s * strideAS;
  const u16* apl = Al + (size_t)s * strideAS;
  const u16* wph = Wh + (size_t)s * Npad * Kd;
  const u16* wpl = Wl + (size_t)s * Npad * Kd;
  const int tid  = threadIdx.x;
  const int wave = tid >> 6, lane = tid & 63;
  constexpr int WGN = BN / WN;
  const int wr = wave / WGN, wc = wave % WGN;
  constexpr int FM = WM / 16, FN = WN / 16;
  f32x4 acc[FM][FN] = {};
  constexpr int CPR = BK / 8;
  const int laneRow = lane & 15;
  const int laneK   = (lane >> 4) * 8;

  for (int k0 = 0; k0 < Kd; k0 += BK) {
    __syncthreads();
    for (int idx = tid; idx < BM * CPR; idx += 256) {
      int r = idx / CPR, c = idx % CPR;
      size_t g = (size_t)(m0 + r) * Kd + k0 + c * 8;
      *reinterpret_cast<u16x8*>(&AsH[r * LDK + c * 8]) = *reinterpret_cast<const u16x8*>(&aph[g]);
      *reinterpret_cast<u16x8*>(&AsL[r * LDK + c * 8]) = *reinterpret_cast<const u16x8*>(&apl[g]);
    }
    for (int idx = tid; idx < BN * CPR; idx += 256) {
      int r = idx / CPR, c = idx % CPR;
      size_t g = (size_t)(n0 + r) * Kd + k0 + c * 8;
      *reinterpret_cast<u16x8*>(&BsH[r * LDK + c * 8]) = *reinterpret_cast<const u16x8*>(&wph[g]);
      *reinterpret_cast<u16x8*>(&BsL[r * LDK + c * 8]) = *reinterpret_cast<const u16x8*>(&wpl[g]);
    }
    __syncthreads();
#pragma unroll
    for (int kk = 0; kk < BK / 32; ++kk) {
      const int kof = kk * 32 + laneK;
      bf16x8 ah[FM], al[FM], bh[FN], bl[FN];
#pragma unroll
      for (int mi = 0; mi < FM; ++mi) {
        const int r = (wr * WM + mi * 16 + laneRow) * LDK + kof;
        ah[mi] = *reinterpret_cast<const bf16x8*>(&AsH[r]);
        al[mi] = *reinterpret_cast<const bf16x8*>(&AsL[r]);
      }
#pragma unroll
      for (int ni = 0; ni < FN; ++ni) {
        const int r = (wc * WN + ni * 16 + laneRow) * LDK + kof;
        bh[ni] = *reinterpret_cast<const bf16x8*>(&BsH[r]);
        bl[ni] = *reinterpret_cast<const bf16x8*>(&BsL[r]);
      }
#pragma unroll
      for (int mi = 0; mi < FM; ++mi)
#pragma unroll
        for (int ni = 0; ni < FN; ++ni) {
          acc[mi][ni] = __builtin_amdgcn_mfma_f32_16x16x32_bf16(ah[mi], bh[ni], acc[mi][ni], 0, 0, 0);
          acc[mi][ni] = __builtin_amdgcn_mfma_f32_16x16x32_bf16(ah[mi], bl[ni], acc[mi][ni], 0, 0, 0);
          acc[mi][ni] = __builtin_amdgcn_mfma_f32_16x16x32_bf16(al[mi], bh[ni], acc[mi][ni], 0, 0, 0);
        }
    }
  }

  const int rbase = (lane >> 4) * 4;
#pragma unroll
  for (int mi = 0; mi < FM; ++mi) {
#pragma unroll
    for (int ni = 0; ni < FN; ++ni) {
#pragma unroll
      for (int r = 0; r < 4; ++r) {
        const int gm = m0 + wr * WM + mi * 16 + rbase + r;
        const int gn = n0 + wc * WN + ni * 16 + laneRow;
        if (gn < Nout) {
          float v = acc[mi][ni][r] + bias[s * Nout + gn];
          const size_t oidx = ((size_t)s * M + gm) * (size_t)Nout + gn;
          if constexpr (RES) {
            const size_t ridx = (size_t)s * strideAS + (size_t)gm * H + gn;
            v += bf2f(resH[ridx]) + bf2f(resL[ridx]);
          }
          if constexpr (F32OUT) {
            reinterpret_cast<float*>(outP)[oidx] = v;
          } else {
            BfPair pr = split2(v);
            reinterpret_cast<u16*>(outP)[oidx] = pr.hi;
            outLo[oidx] = pr.lo;
          }
        }
      }
    }
  }
}

// ------- fused gelu + layernorm, in place on hi/lo pair, one wave per row ----
__global__ __launch_bounds__(256) void gelu_ln_kernel(
    u16* __restrict__ bh, u16* __restrict__ bl,
    const float* __restrict__ lns, const float* __restrict__ lnb) {
  const int row  = blockIdx.x * 4 + (threadIdx.x >> 6);
  const int lane = threadIdx.x & 63;
  const size_t base = (size_t)row * H + lane * 8;
  u16x8 rh = *reinterpret_cast<const u16x8*>(&bh[base]);
  u16x8 rl = *reinterpret_cast<const u16x8*>(&bl[base]);
  float v[8];
  float sum = 0.f, sq = 0.f;
#pragma unroll
  for (int j = 0; j < 8; ++j) {
    float g = gelu_tanh(bf2f(rh[j]) + bf2f(rl[j]));
    v[j] = g; sum += g; sq += g * g;
  }
#pragma unroll
  for (int o = 32; o > 0; o >>= 1) {
    sum += __shfl_xor(sum, o, 64);
    sq  += __shfl_xor(sq, o, 64);
  }
  const float mean = sum * (1.f / 512.f);
  const float var  = sq * (1.f / 512.f) - mean * mean;
  const float rstd = 1.f / sqrtf(var + 1e-6f);
  const int site = row / BATCH;   // site index (lns is site-base pointer)
  const float* sp = lns + site * H + lane * 8;
  const float* bp = lnb + site * H + lane * 8;
  u16x8 oh, ol;
#pragma unroll
  for (int j = 0; j < 8; ++j) {
    float z = (v[j] - mean) * rstd * sp[j] + bp[j];
    BfPair pr = split2(z);
    oh[j] = pr.hi;
    ol[j] = pr.lo;
  }
  *reinterpret_cast<u16x8*>(&bh[base]) = oh;
  *reinterpret_cast<u16x8*>(&bl[base]) = ol;
}

// ---------------- RQS spline: one thread per (b,i), params via LDS -----------
DI float invsymlu(float u) { return u >= 0.f ? u + 1.f : 1.f / (1.f - u); }

__global__ __launch_bounds__(128) void spline_kernel(
    const float* __restrict__ x, const float* __restrict__ bias0,
    const float* __restrict__ p, float* __restrict__ out0, float* __restrict__ ladbuf) {
  __shared__ float prm[128 * 101];   // stride 101: conflict-free
  const int i  = blockIdx.x;         // 0..15
  const int b0 = blockIdx.y * 128;
  if (i == 0) {
    for (int idx = threadIdx.x; idx < 128 * OUTC; idx += 128)
      prm[(idx / OUTC) * 101 + idx % OUTC] = bias0[idx % OUTC];
  } else {
    const float* src = p + ((size_t)(i - 1) * BATCH + b0) * OUTC;
    for (int idx = threadIdx.x; idx < 128 * OUTC; idx += 128)
      prm[(idx / OUTC) * 101 + idx % OUTC] = src[idx];
  }
  __syncthreads();
  const float* P = &prm[threadIdx.x * 101];
  const int b = b0 + threadIdx.x;
  const float inp = x[b * 16 + i];

  float tw = 0.f, th = 0.f;
  for (int k = 0; k < 32; ++k) tw += 0.001f + invsymlu(P[k]);
  for (int k = 0; k < 32; ++k) th += 0.001f + invsymlu(P[32 + k]);
  const float cx = P[97], cy = P[98];
  const float w0 = cx - 0.5f * tw, wK = cx + 0.5f * tw;
  const float h0 = cy - 0.5f * th, hK = cy + 0.5f * th;
  const float d0 = 0.001f + invsymlu(P[64]);
  const float dK = 0.001f + invsymlu(P[96]);
  float outv, lad;
  if (inp < w0) {
    outv = h0 - (w0 - inp) * d0;
    lad  = logf(d0);
  } else if (inp >= wK) {
    outv = (inp - wK) * dK + hK;
    lad  = logf(dK);
  } else {
    float run = w0, icw = w0, ibw = 1.f;
    int bin = 0;
    for (int k = 0; k < 32; ++k) {
      float wk = 0.001f + invsymlu(P[k]);
      if (inp >= run) { bin = k; icw = run; ibw = wk; }
      run += wk;
    }
    float runh = h0;
    for (int k = 0; k < bin; ++k) runh += 0.001f + invsymlu(P[32 + k]);
    const float ih    = 0.001f + invsymlu(P[32 + bin]);
    const float ich   = runh;
    const float ider  = 0.001f + invsymlu(P[64 + bin]);
    const float iderp = 0.001f + invsymlu(P[64 + bin + 1]);
    const float idl   = ih / ibw;
    const float theta = (inp - icw) / ibw;
    const float omt   = 1.f - theta;
    const float tomt  = theta * omt;
    const float num   = ih * (idl * theta * theta + ider * tomt);
    const float den   = idl + (ider + iderp - 2.f * idl) * tomt;
    outv = ich + num / den;
    const float dnum = idl * idl * (iderp * theta * theta + 2.f * idl * tomt + ider * omt * omt);
    lad = logf(dnum) - 2.f * logf(den);
  }
  out0[b * 16 + i]   = outv;
  ladbuf[b * 16 + i] = lad;
}

__global__ void lad_reduce_kernel(const float* __restrict__ ladbuf, float* __restrict__ out1) {
  const int b = blockIdx.x * 256 + threadIdx.x;
  float s = 0.f;
#pragma unroll
  for (int i = 0; i < 16; ++i) s += ladbuf[b * 16 + i];
  out1[b] = s;
}

// ---------------------------------------------------------------------------
extern "C" void kernel_launch(void* const* d_in, const int* in_sizes, int n_in,
                              void* d_out, int out_size, void* d_ws, size_t ws_size,
                              hipStream_t stream) {
  const float* x     = (const float*)d_in[0];
  const float* bias0 = (const float*)d_in[1];
  const float* W0    = (const float*)d_in[2];
  const float* b0    = (const float*)d_in[3];
  const float* ln0s  = (const float*)d_in[4];
  const float* ln0b  = (const float*)d_in[5];
  const float* W1    = (const float*)d_in[6];
  const float* b1    = (const float*)d_in[7];
  const float* ln1s  = (const float*)d_in[8];
  const float* ln1b  = (const float*)d_in[9];
  const float* W2    = (const float*)d_in[10];
  const float* b2    = (const float*)d_in[11];
  const float* ln2s  = (const float*)d_in[12];
  const float* ln2b  = (const float*)d_in[13];
  const float* Wf    = (const float*)d_in[14];
  const float* bfb   = (const float*)d_in[15];
  float* out0 = (float*)d_out;
  float* out1 = out0 + BATCH * 16;

  // ---- workspace budget: maximize sites-per-pass ---------------------------
  const size_t fixedBytes =
      2 * ((size_t)BATCH * DPAD * 2) +          // eh, el
      2 * ((size_t)S1 * H * DPAD * 2) +         // W0T h,l
      4 * ((size_t)S1 * H * H * 2) +            // W1T, W2T h,l
      2 * ((size_t)S1 * OUTPAD * H * 2) +       // WfT h,l
      (size_t)S1 * BATCH * OUTC * 4 +           // pbuf
      (size_t)BATCH * 16 * 4 +                  // ladb
      64 * 256;                                  // alignment slack
  const size_t perSiteP = 4 * ((size_t)BATCH * H * 2);  // P1/P2 h,l per site
  int CH = 1;
  if (ws_size > fixedBytes) {
    size_t c = (ws_size - fixedBytes) / perSiteP;
    CH = (c >= (size_t)S1) ? S1 : (c < 1 ? 1 : (int)c);
  }
  // equalize pass sizes: nPasses passes of size base or base+1
  const int nPasses = (S1 + CH - 1) / CH;
  const int baseSz  = S1 / nPasses;
  const int remSz   = S1 % nPasses;

  char* ws = (char*)d_ws;
  size_t off = 0;
  auto take = [&](size_t bytes) {
    char* q = ws + off;
    off += (bytes + 255) & ~(size_t)255;
    return q;
  };
  u16* eh   = (u16*)take((size_t)BATCH * DPAD * 2);
  u16* el   = (u16*)take((size_t)BATCH * DPAD * 2);
  u16* W0Th = (u16*)take((size_t)S1 * H * DPAD * 2);
  u16* W0Tl = (u16*)take((size_t)S1 * H * DPAD * 2);
  u16* W1Th = (u16*)take((size_t)S1 * H * H * 2);
  u16* W1Tl = (u16*)take((size_t)S1 * H * H * 2);
  u16* W2Th = (u16*)take((size_t)S1 * H * H * 2);
  u16* W2Tl = (u16*)take((size_t)S1 * H * H * 2);
  u16* WfTh = (u16*)take((size_t)S1 * OUTPAD * H * 2);
  u16* WfTl = (u16*)take((size_t)S1 * OUTPAD * H * 2);
  u16* P1h  = (u16*)take((size_t)CH * BATCH * H * 2);
  u16* P1l  = (u16*)take((size_t)CH * BATCH * H * 2);
  u16* P2h  = (u16*)take((size_t)CH * BATCH * H * 2);
  u16* P2l  = (u16*)take((size_t)CH * BATCH * H * 2);
  float* pbuf = (float*)take((size_t)S1 * BATCH * OUTC * 4);
  float* ladb = (float*)take((size_t)BATCH * 16 * 4);

  embed_kernel<<<BATCH, 128, 0, stream>>>(x, eh, el);
  transpose_conv_kernel<<<dim3(4, 16, S1), 256, 0, stream>>>(W0, W0Th, W0Tl, 120, H, DPAD, H, 8);
  transpose_conv_kernel<<<dim3(16, 16, S1), 256, 0, stream>>>(W1, W1Th, W1Tl, H, H, H, H, 0);
  transpose_conv_kernel<<<dim3(16, 16, S1), 256, 0, stream>>>(W2, W2Th, W2Tl, H, H, H, H, 0);
  transpose_conv_kernel<<<dim3(16, 4, S1), 256, 0, stream>>>(Wf, WfTh, WfTl, H, OUTC, H, OUTPAD, 0);

  int sb = 0;
  for (int pass = 0; pass < nPasses; ++pass) {
    const int nz = baseSz + (pass < remSz ? 1 : 0);
    // layer 0: e (shared) -> P2
    gemm_kernel<128, 128, 32, 64, 64, false, false><<<dim3(32, 4, nz), 256, 0, stream>>>(
        eh, el, W0Th + (size_t)sb * H * DPAD, W0Tl + (size_t)sb * H * DPAD,
        b0 + sb * H, nullptr, nullptr, P2h, P2l, BATCH, DPAD, H, H, 0);
    gelu_ln_kernel<<<nz * BATCH / 4, 256, 0, stream>>>(P2h, P2l, ln0s + sb * H, ln0b + sb * H);
    // layer 1: P2 -> P1 (residual P2)
    gemm_kernel<128, 128, 32, 64, 64, true, false><<<dim3(32, 4, nz), 256, 0, stream>>>(
        P2h, P2l, W1Th + (size_t)sb * H * H, W1Tl + (size_t)sb * H * H,
        b1 + sb * H, P2h, P2l, P1h, P1l, BATCH, H, H, H, BATCH * H);
    gelu_ln_kernel<<<nz * BATCH / 4, 256, 0, stream>>>(P1h, P1l, ln1s + sb * H, ln1b + sb * H);
    // layer 2: P1 -> P2 (residual P1)
    gemm_kernel<128, 128, 32, 64, 64, true, false><<<dim3(32, 4, nz), 256, 0, stream>>>(
        P1h, P1l, W2Th + (size_t)sb * H * H, W2Tl + (size_t)sb * H * H,
        b2 + sb * H, P1h, P1l, P2h, P2l, BATCH, H, H, H, BATCH * H);
    gelu_ln_kernel<<<nz * BATCH / 4, 256, 0, stream>>>(P2h, P2l, ln2s + sb * H, ln2b + sb * H);
    // final projection: P2 -> pbuf (f32)
    gemm_kernel<128, 112, 32, 32, 112, false, true><<<dim3(32, 1, nz), 256, 0, stream>>>(
        P2h, P2l, WfTh + (size_t)sb * OUTPAD * H, WfTl + (size_t)sb * OUTPAD * H,
        bfb + sb * OUTC, nullptr, nullptr, pbuf + (size_t)sb * BATCH * OUTC, nullptr,
        BATCH, H, OUTPAD, OUTC, BATCH * H);
    sb += nz;
  }

  spline_kernel<<<dim3(16, 32), 128, 0, stream>>>(x, bias0, pbuf, out0, ladb);
  lad_reduce_kernel<<<BATCH / 256, 256, 0, stream>>>(ladb, out1);
}

// Round 6
// 528.873 us; speedup vs baseline: 1.2578x; 1.2199x over previous
//
#include <hip/hip_runtime.h>
#include <hip/hip_bf16.h>
#include <cstdint>
#include <cstddef>

typedef unsigned short u16;
typedef __attribute__((ext_vector_type(8))) short bf16x8;      // MFMA A/B frag
typedef __attribute__((ext_vector_type(4))) float f32x4;       // MFMA C/D frag
typedef __attribute__((ext_vector_type(8))) unsigned short u16x8;

#define DI __device__ __forceinline__

constexpr int BATCH  = 4096;
constexpr int S1     = 15;
constexpr int DPAD   = 128;   // 120 padded to 128
constexpr int H      = 512;
constexpr int OUTC   = 99;
constexpr int OUTPAD = 112;   // 99 padded to 7*16

DI u16 f2bf(float f) {
  __hip_bfloat16 h = __float2bfloat16(f);
  return __builtin_bit_cast(u16, h);
}
DI float bf2f(u16 u) {
  __hip_bfloat16 h = __builtin_bit_cast(__hip_bfloat16, u);
  return __bfloat162float(h);
}
struct BfPair { u16 hi, lo; };
// split f32 -> hi bf16 + lo bf16 (residual); hi+lo carries ~17 mantissa bits
DI BfPair split2(float v) {
  BfPair r;
  r.hi = f2bf(v);
  r.lo = f2bf(v - bf2f(r.hi));
  return r;
}

// jax.nn.gelu default = tanh approximation
DI float gelu_tanh(float x) {
  float z = 0.7978845608028654f * (x + 0.044715f * x * x * x);
  return 0.5f * x * (1.f + tanhf(z));
}

// async 16B global -> LDS (wave-uniform LDS base + lane*16)
DI void gload16(const void* g, void* l) {
  __builtin_amdgcn_global_load_lds(
      (const __attribute__((address_space(1))) void*)g,
      (__attribute__((address_space(3))) void*)l, 16, 0, 0);
}

// ---------------- embeddings: e[b][d] split hi/lo, d in [0,128) --------------
__global__ void embed_kernel(const float* __restrict__ x,
                             u16* __restrict__ eh, u16* __restrict__ el) {
  const int b = blockIdx.x, d = threadIdx.x;  // 128 threads
  float v = 0.f;
  if (d < 120) {
    const float divs[4] = {1.f, 0.31622776601683794f, 0.1f, 0.03162277660168379f};
    int site = d >> 3, j = d & 7;
    float arg = x[b * 16 + site] * divs[j & 3];
    v = (j < 4) ? sinf(arg) : cosf(arg);
  }
  BfPair r = split2(v);
  eh[b * DPAD + d] = r.hi;
  el[b * DPAD + d] = r.lo;
}

// ---- transpose+convert+split: dst{h,l}[s][n][k] = split(src[s][k][n]) -------
__global__ __launch_bounds__(256) void transpose_conv_kernel(
    const float* __restrict__ src, u16* __restrict__ dsth, u16* __restrict__ dstl,
    int K, int N, int Kpad, int Npad, int maskMul) {
  __shared__ float tile[32][33];
  const int s  = blockIdx.z;
  const int kb = blockIdx.x * 32, nb = blockIdx.y * 32;
  const int tx = threadIdx.x & 31, ty = threadIdx.x >> 5;  // 32 x 8
  for (int i = ty; i < 32; i += 8) {
    int k = kb + i, n = nb + tx;
    tile[i][tx] = (k < K && n < N) ? src[((size_t)s * K + k) * N + n] : 0.f;
  }
  __syncthreads();
  const int klim = maskMul ? maskMul * (s + 1) : 0x7FFFFFFF;
  for (int i = ty; i < 32; i += 8) {
    int n = nb + i, k = kb + tx;
    if (n < Npad && k < Kpad) {
      float v = (k < klim) ? tile[tx][i] : 0.f;
      size_t o = ((size_t)s * Npad + n) * Kpad + k;
      BfPair r = split2(v);
      dsth[o] = r.hi;
      dstl[o] = r.lo;
    }
  }
}

// ------------- split-precision bf16 MFMA GEMM, m97-style staging -------------
// acc = Ah*Bh + Ah*Bl + Al*Bh  (~f32 accuracy)
// Staging: global_load_lds 16B into LINEAR LDS [rows][BK]; bank conflicts fixed
// by XOR-swizzling the global SOURCE chunk (c^(r&7)) + same XOR on ds_read
// (both-sides-or-neither, rule #21).
template<int BM, int BN, int BK, int WM, int WN, bool RES, bool F32OUT>
__global__ __launch_bounds__(256) void gemm_kernel(
    const u16* __restrict__ Ah, const u16* __restrict__ Al,
    const u16* __restrict__ Wh, const u16* __restrict__ Wl,
    const float* __restrict__ bias,
    const u16* __restrict__ resH, const u16* __restrict__ resL,
    void* __restrict__ outP, u16* __restrict__ outLo,
    int M, int Kd, int Npad, int Nout, int strideAS) {
  constexpr int CPR = BK / 8;        // 16B chunks per row (8 for BK=64)
  constexpr int SWZ = CPR - 1;       // XOR mask (7)
  extern __shared__ u16 smem[];
  u16* AsH = smem;
  u16* AsL = AsH + BM * BK;
  u16* BsH = AsL + BM * BK;
  u16* BsL = BsH + BN * BK;

  const int s  = blockIdx.z;
  const int m0 = blockIdx.x * BM;
  const int n0 = blockIdx.y * BN;
  const u16* aph = Ah + (size_t)s * strideAS + (size_t)m0 * Kd;
  const u16* apl = Al + (size_t)s * strideAS + (size_t)m0 * Kd;
  const u16* wph = Wh + (size_t)s * Npad * Kd + (size_t)n0 * Kd;
  const u16* wpl = Wl + (size_t)s * Npad * Kd + (size_t)n0 * Kd;
  const int tid   = threadIdx.x;
  const int wbase = tid & ~63;       // wave's first tid (uniform per wave)
  const int wave  = tid >> 6, lane = tid & 63;
  constexpr int WGN = BN / WN;
  const int wr = wave / WGN, wc = wave % WGN;
  constexpr int FM = WM / 16, FN = WN / 16;
  f32x4 acc[FM][FN] = {};
  const int laneRow = lane & 15;
  const int hi      = lane >> 4;     // k-chunk sub-index

  for (int k0 = 0; k0 < Kd; k0 += BK) {
    __syncthreads();   // previous compute done before overwrite
    // ---- stage 4 buffers via global_load_lds (linear dest, swizzled src) ----
    {
      // A buffers: BM*CPR chunks
      for (int base = 0; base < BM * CPR; base += 256) {
        const int idx = base + tid;
        if (idx < BM * CPR) {
          const int r = idx / CPR, c = idx % CPR;
          const int cg = c ^ (r & SWZ);
          const size_t go = (size_t)r * Kd + k0 + cg * 8;
          u16* ldst = (u16*)((base + wbase) * 16 / 2 + (char*)nullptr ? nullptr : nullptr);
          (void)ldst;
          gload16(aph + go, AsH + (size_t)(base + wbase) * 8);
          gload16(apl + go, AsL + (size_t)(base + wbase) * 8);
        }
      }
      // B buffers: BN*CPR chunks
      for (int base = 0; base < BN * CPR; base += 256) {
        const int idx = base + tid;
        if (idx < BN * CPR) {
          const int r = idx / CPR, c = idx % CPR;
          const int cg = c ^ (r & SWZ);
          const size_t go = (size_t)r * Kd + k0 + cg * 8;
          gload16(wph + go, BsH + (size_t)(base + wbase) * 8);
          gload16(wpl + go, BsL + (size_t)(base + wbase) * 8);
        }
      }
    }
    __syncthreads();   // drains vmcnt -> staged tiles visible
#pragma unroll
    for (int kk = 0; kk < BK / 32; ++kk) {
      const int cc = kk * 4 + hi;    // 16B chunk index within row
      bf16x8 a_h[FM], a_l[FM], b_h[FN], b_l[FN];
#pragma unroll
      for (int mi = 0; mi < FM; ++mi) {
        const int row = wr * WM + mi * 16 + laneRow;
        const int off = row * BK + ((cc ^ (row & SWZ)) << 3);
        a_h[mi] = *reinterpret_cast<const bf16x8*>(&AsH[off]);
        a_l[mi] = *reinterpret_cast<const bf16x8*>(&AsL[off]);
      }
#pragma unroll
      for (int ni = 0; ni < FN; ++ni) {
        const int row = wc * WN + ni * 16 + laneRow;
        const int off = row * BK + ((cc ^ (row & SWZ)) << 3);
        b_h[ni] = *reinterpret_cast<const bf16x8*>(&BsH[off]);
        b_l[ni] = *reinterpret_cast<const bf16x8*>(&BsL[off]);
      }
#pragma unroll
      for (int mi = 0; mi < FM; ++mi)
#pragma unroll
        for (int ni = 0; ni < FN; ++ni) {
          acc[mi][ni] = __builtin_amdgcn_mfma_f32_16x16x32_bf16(a_h[mi], b_h[ni], acc[mi][ni], 0, 0, 0);
          acc[mi][ni] = __builtin_amdgcn_mfma_f32_16x16x32_bf16(a_h[mi], b_l[ni], acc[mi][ni], 0, 0, 0);
          acc[mi][ni] = __builtin_amdgcn_mfma_f32_16x16x32_bf16(a_l[mi], b_h[ni], acc[mi][ni], 0, 0, 0);
        }
    }
  }

  const int rbase = hi * 4;
#pragma unroll
  for (int mi = 0; mi < FM; ++mi) {
#pragma unroll
    for (int ni = 0; ni < FN; ++ni) {
#pragma unroll
      for (int r = 0; r < 4; ++r) {
        const int gm = m0 + wr * WM + mi * 16 + rbase + r;
        const int gn = n0 + wc * WN + ni * 16 + laneRow;
        if (gn < Nout) {
          float v = acc[mi][ni][r] + bias[s * Nout + gn];
          const size_t oidx = ((size_t)s * M + gm) * (size_t)Nout + gn;
          if constexpr (RES) {
            const size_t ridx = (size_t)s * strideAS + (size_t)gm * H + gn;
            v += bf2f(resH[ridx]) + bf2f(resL[ridx]);
          }
          if constexpr (F32OUT) {
            reinterpret_cast<float*>(outP)[oidx] = v;
          } else {
            BfPair pr = split2(v);
            reinterpret_cast<u16*>(outP)[oidx] = pr.hi;
            outLo[oidx] = pr.lo;
          }
        }
      }
    }
  }
}

// ------- fused gelu + layernorm, in place on hi/lo pair, one wave per row ----
__global__ __launch_bounds__(256) void gelu_ln_kernel(
    u16* __restrict__ bh, u16* __restrict__ bl,
    const float* __restrict__ lns, const float* __restrict__ lnb) {
  const int row  = blockIdx.x * 4 + (threadIdx.x >> 6);
  const int lane = threadIdx.x & 63;
  const size_t base = (size_t)row * H + lane * 8;
  u16x8 rh = *reinterpret_cast<const u16x8*>(&bh[base]);
  u16x8 rl = *reinterpret_cast<const u16x8*>(&bl[base]);
  float v[8];
  float sum = 0.f, sq = 0.f;
#pragma unroll
  for (int j = 0; j < 8; ++j) {
    float g = gelu_tanh(bf2f(rh[j]) + bf2f(rl[j]));
    v[j] = g; sum += g; sq += g * g;
  }
#pragma unroll
  for (int o = 32; o > 0; o >>= 1) {
    sum += __shfl_xor(sum, o, 64);
    sq  += __shfl_xor(sq, o, 64);
  }
  const float mean = sum * (1.f / 512.f);
  const float var  = sq * (1.f / 512.f) - mean * mean;
  const float rstd = 1.f / sqrtf(var + 1e-6f);
  const int site = row / BATCH;   // site index (lns is site-base pointer)
  const float* sp = lns + site * H + lane * 8;
  const float* bp = lnb + site * H + lane * 8;
  u16x8 oh, ol;
#pragma unroll
  for (int j = 0; j < 8; ++j) {
    float z = (v[j] - mean) * rstd * sp[j] + bp[j];
    BfPair pr = split2(z);
    oh[j] = pr.hi;
    ol[j] = pr.lo;
  }
  *reinterpret_cast<u16x8*>(&bh[base]) = oh;
  *reinterpret_cast<u16x8*>(&bl[base]) = ol;
}

// ---------------- RQS spline: one thread per (b,i), params via LDS -----------
DI float invsymlu(float u) { return u >= 0.f ? u + 1.f : 1.f / (1.f - u); }

__global__ __launch_bounds__(128) void spline_kernel(
    const float* __restrict__ x, const float* __restrict__ bias0,
    const float* __restrict__ p, float* __restrict__ out0, float* __restrict__ ladbuf) {
  __shared__ float prm[128 * 101];   // stride 101: conflict-free
  const int i  = blockIdx.x;         // 0..15
  const int b0 = blockIdx.y * 128;
  if (i == 0) {
    for (int idx = threadIdx.x; idx < 128 * OUTC; idx += 128)
      prm[(idx / OUTC) * 101 + idx % OUTC] = bias0[idx % OUTC];
  } else {
    const float* src = p + ((size_t)(i - 1) * BATCH + b0) * OUTC;
    for (int idx = threadIdx.x; idx < 128 * OUTC; idx += 128)
      prm[(idx / OUTC) * 101 + idx % OUTC] = src[idx];
  }
  __syncthreads();
  const float* P = &prm[threadIdx.x * 101];
  const int b = b0 + threadIdx.x;
  const float inp = x[b * 16 + i];

  float tw = 0.f, th = 0.f;
  for (int k = 0; k < 32; ++k) tw += 0.001f + invsymlu(P[k]);
  for (int k = 0; k < 32; ++k) th += 0.001f + invsymlu(P[32 + k]);
  const float cx = P[97], cy = P[98];
  const float w0 = cx - 0.5f * tw, wK = cx + 0.5f * tw;
  const float h0 = cy - 0.5f * th, hK = cy + 0.5f * th;
  const float d0 = 0.001f + invsymlu(P[64]);
  const float dK = 0.001f + invsymlu(P[96]);
  float outv, lad;
  if (inp < w0) {
    outv = h0 - (w0 - inp) * d0;
    lad  = logf(d0);
  } else if (inp >= wK) {
    outv = (inp - wK) * dK + hK;
    lad  = logf(dK);
  } else {
    float run = w0, icw = w0, ibw = 1.f;
    int bin = 0;
    for (int k = 0; k < 32; ++k) {
      float wk = 0.001f + invsymlu(P[k]);
      if (inp >= run) { bin = k; icw = run; ibw = wk; }
      run += wk;
    }
    float runh = h0;
    for (int k = 0; k < bin; ++k) runh += 0.001f + invsymlu(P[32 + k]);
    const float ih    = 0.001f + invsymlu(P[32 + bin]);
    const float ich   = runh;
    const float ider  = 0.001f + invsymlu(P[64 + bin]);
    const float iderp = 0.001f + invsymlu(P[64 + bin + 1]);
    const float idl   = ih / ibw;
    const float theta = (inp - icw) / ibw;
    const float omt   = 1.f - theta;
    const float tomt  = theta * omt;
    const float num   = ih * (idl * theta * theta + ider * tomt);
    const float den   = idl + (ider + iderp - 2.f * idl) * tomt;
    outv = ich + num / den;
    const float dnum = idl * idl * (iderp * theta * theta + 2.f * idl * tomt + ider * omt * omt);
    lad = logf(dnum) - 2.f * logf(den);
  }
  out0[b * 16 + i]   = outv;
  ladbuf[b * 16 + i] = lad;
}

__global__ void lad_reduce_kernel(const float* __restrict__ ladbuf, float* __restrict__ out1) {
  const int b = blockIdx.x * 256 + threadIdx.x;
  float s = 0.f;
#pragma unroll
  for (int i = 0; i < 16; ++i) s += ladbuf[b * 16 + i];
  out1[b] = s;
}

// ---------------------------------------------------------------------------
extern "C" void kernel_launch(void* const* d_in, const int* in_sizes, int n_in,
                              void* d_out, int out_size, void* d_ws, size_t ws_size,
                              hipStream_t stream) {
  const float* x     = (const float*)d_in[0];
  const float* bias0 = (const float*)d_in[1];
  const float* W0    = (const float*)d_in[2];
  const float* b0    = (const float*)d_in[3];
  const float* ln0s  = (const float*)d_in[4];
  const float* ln0b  = (const float*)d_in[5];
  const float* W1    = (const float*)d_in[6];
  const float* b1    = (const float*)d_in[7];
  const float* ln1s  = (const float*)d_in[8];
  const float* ln1b  = (const float*)d_in[9];
  const float* W2    = (const float*)d_in[10];
  const float* b2    = (const float*)d_in[11];
  const float* ln2s  = (const float*)d_in[12];
  const float* ln2b  = (const float*)d_in[13];
  const float* Wf    = (const float*)d_in[14];
  const float* bfb   = (const float*)d_in[15];
  float* out0 = (float*)d_out;
  float* out1 = out0 + BATCH * 16;

  // ---- workspace budget: maximize sites-per-pass ---------------------------
  const size_t fixedBytes =
      2 * ((size_t)BATCH * DPAD * 2) +
      2 * ((size_t)S1 * H * DPAD * 2) +
      4 * ((size_t)S1 * H * H * 2) +
      2 * ((size_t)S1 * OUTPAD * H * 2) +
      (size_t)S1 * BATCH * OUTC * 4 +
      (size_t)BATCH * 16 * 4 +
      64 * 256;
  const size_t perSiteP = 4 * ((size_t)BATCH * H * 2);
  int CH = 1;
  if (ws_size > fixedBytes) {
    size_t c = (ws_size - fixedBytes) / perSiteP;
    CH = (c >= (size_t)S1) ? S1 : (c < 1 ? 1 : (int)c);
  }
  const int nPasses = (S1 + CH - 1) / CH;
  const int baseSz  = S1 / nPasses;
  const int remSz   = S1 % nPasses;

  char* ws = (char*)d_ws;
  size_t off = 0;
  auto take = [&](size_t bytes) {
    char* q = ws + off;
    off += (bytes + 255) & ~(size_t)255;
    return q;
  };
  u16* eh   = (u16*)take((size_t)BATCH * DPAD * 2);
  u16* el   = (u16*)take((size_t)BATCH * DPAD * 2);
  u16* W0Th = (u16*)take((size_t)S1 * H * DPAD * 2);
  u16* W0Tl = (u16*)take((size_t)S1 * H * DPAD * 2);
  u16* W1Th = (u16*)take((size_t)S1 * H * H * 2);
  u16* W1Tl = (u16*)take((size_t)S1 * H * H * 2);
  u16* W2Th = (u16*)take((size_t)S1 * H * H * 2);
  u16* W2Tl = (u16*)take((size_t)S1 * H * H * 2);
  u16* WfTh = (u16*)take((size_t)S1 * OUTPAD * H * 2);
  u16* WfTl = (u16*)take((size_t)S1 * OUTPAD * H * 2);
  u16* P1h  = (u16*)take((size_t)CH * BATCH * H * 2);
  u16* P1l  = (u16*)take((size_t)CH * BATCH * H * 2);
  u16* P2h  = (u16*)take((size_t)CH * BATCH * H * 2);
  u16* P2l  = (u16*)take((size_t)CH * BATCH * H * 2);
  float* pbuf = (float*)take((size_t)S1 * BATCH * OUTC * 4);
  float* ladb = (float*)take((size_t)BATCH * 16 * 4);

  embed_kernel<<<BATCH, 128, 0, stream>>>(x, eh, el);
  transpose_conv_kernel<<<dim3(4, 16, S1), 256, 0, stream>>>(W0, W0Th, W0Tl, 120, H, DPAD, H, 8);
  transpose_conv_kernel<<<dim3(16, 16, S1), 256, 0, stream>>>(W1, W1Th, W1Tl, H, H, H, H, 0);
  transpose_conv_kernel<<<dim3(16, 16, S1), 256, 0, stream>>>(W2, W2Th, W2Tl, H, H, H, H, 0);
  transpose_conv_kernel<<<dim3(16, 4, S1), 256, 0, stream>>>(Wf, WfTh, WfTl, H, OUTC, H, OUTPAD, 0);

  // dynamic LDS bytes: (BM+BN)*BK*2 elems * 2B
  const size_t ldsMain = (size_t)(128 + 128) * 64 * 2 * 2;  // 65536
  const size_t ldsOut  = (size_t)(64 + 112) * 64 * 2 * 2;   // 45056

  int sb = 0;
  for (int pass = 0; pass < nPasses; ++pass) {
    const int nz = baseSz + (pass < remSz ? 1 : 0);
    // layer 0: e (shared) -> P2
    gemm_kernel<128, 128, 64, 64, 64, false, false>
        <<<dim3(32, 4, nz), 256, ldsMain, stream>>>(
        eh, el, W0Th + (size_t)sb * H * DPAD, W0Tl + (size_t)sb * H * DPAD,
        b0 + sb * H, nullptr, nullptr, P2h, P2l, BATCH, DPAD, H, H, 0);
    gelu_ln_kernel<<<nz * BATCH / 4, 256, 0, stream>>>(P2h, P2l, ln0s + sb * H, ln0b + sb * H);
    // layer 1: P2 -> P1 (residual P2)
    gemm_kernel<128, 128, 64, 64, 64, true, false>
        <<<dim3(32, 4, nz), 256, ldsMain, stream>>>(
        P2h, P2l, W1Th + (size_t)sb * H * H, W1Tl + (size_t)sb * H * H,
        b1 + sb * H, P2h, P2l, P1h, P1l, BATCH, H, H, H, BATCH * H);
    gelu_ln_kernel<<<nz * BATCH / 4, 256, 0, stream>>>(P1h, P1l, ln1s + sb * H, ln1b + sb * H);
    // layer 2: P1 -> P2 (residual P1)
    gemm_kernel<128, 128, 64, 64, 64, true, false>
        <<<dim3(32, 4, nz), 256, ldsMain, stream>>>(
        P1h, P1l, W2Th + (size_t)sb * H * H, W2Tl + (size_t)sb * H * H,
        b2 + sb * H, P1h, P1l, P2h, P2l, BATCH, H, H, H, BATCH * H);
    gelu_ln_kernel<<<nz * BATCH / 4, 256, 0, stream>>>(P2h, P2l, ln2s + sb * H, ln2b + sb * H);
    // final projection: P2 -> pbuf (f32)
    gemm_kernel<64, 112, 64, 16, 112, false, true>
        <<<dim3(64, 1, nz), 256, ldsOut, stream>>>(
        P2h, P2l, WfTh + (size_t)sb * OUTPAD * H, WfTl + (size_t)sb * OUTPAD * H,
        bfb + sb * OUTC, nullptr, nullptr, pbuf + (size_t)sb * BATCH * OUTC, nullptr,
        BATCH, H, OUTPAD, OUTC, BATCH * H);
    sb += nz;
  }

  spline_kernel<<<dim3(16, 32), 128, 0, stream>>>(x, bias0, pbuf, out0, ladb);
  lad_reduce_kernel<<<BATCH / 256, 256, 0, stream>>>(ladb, out1);
}

// Round 8
// 517.172 us; speedup vs baseline: 1.2862x; 1.0226x over previous
//
#include <hip/hip_runtime.h>
#include <hip/hip_bf16.h>
#include <cstdint>
#include <cstddef>

typedef _Float16 f16;
typedef __attribute__((ext_vector_type(8))) _Float16 f16x8;   // MFMA A/B frag
typedef __attribute__((ext_vector_type(4))) float f32x4;      // MFMA C/D frag

#define DI __device__ __forceinline__

constexpr int BATCH  = 4096;
constexpr int S1     = 15;
constexpr int DPAD   = 128;   // 120 padded to 128
constexpr int H      = 512;
constexpr int OUTC   = 99;
constexpr int OUTPAD = 112;   // 99 padded to 7*16

// jax.nn.gelu default = tanh approximation
DI float gelu_tanh(float x) {
  float z = 0.7978845608028654f * (x + 0.044715f * x * x * x);
  return 0.5f * x * (1.f + tanhf(z));
}

// async 16B global -> LDS (wave-uniform LDS base + lane*16)
DI void gload16(const void* g, void* l) {
  __builtin_amdgcn_global_load_lds(
      (const __attribute__((address_space(1))) void*)g,
      (__attribute__((address_space(3))) void*)l, 16, 0, 0);
}

// ---------------- embeddings: e[b][d] f16, d in [0,128), pad zeros -----------
__global__ void embed_kernel(const float* __restrict__ x, f16* __restrict__ e) {
  const int b = blockIdx.x, d = threadIdx.x;  // 128 threads
  float v = 0.f;
  if (d < 120) {
    const float divs[4] = {1.f, 0.31622776601683794f, 0.1f, 0.03162277660168379f};
    int site = d >> 3, j = d & 7;
    float arg = x[b * 16 + site] * divs[j & 3];
    v = (j < 4) ? sinf(arg) : cosf(arg);
  }
  e[b * DPAD + d] = (f16)v;
}

// ---- transpose+convert+split: dst{h,l}[s][n][k] = split_f16(src[s][k][n]) ---
// hi carries 11 mantissa bits, hi+lo ~22 bits (~f32 for weights)
__global__ __launch_bounds__(256) void transpose_conv_kernel(
    const float* __restrict__ src, f16* __restrict__ dsth, f16* __restrict__ dstl,
    int K, int N, int Kpad, int Npad, int maskMul) {
  __shared__ float tile[32][33];
  const int s  = blockIdx.z;
  const int kb = blockIdx.x * 32, nb = blockIdx.y * 32;
  const int tx = threadIdx.x & 31, ty = threadIdx.x >> 5;  // 32 x 8
  for (int i = ty; i < 32; i += 8) {
    int k = kb + i, n = nb + tx;
    tile[i][tx] = (k < K && n < N) ? src[((size_t)s * K + k) * N + n] : 0.f;
  }
  __syncthreads();
  const int klim = maskMul ? maskMul * (s + 1) : 0x7FFFFFFF;
  for (int i = ty; i < 32; i += 8) {
    int n = nb + i, k = kb + tx;
    if (n < Npad && k < Kpad) {
      float v = (k < klim) ? tile[tx][i] : 0.f;
      size_t o = ((size_t)s * Npad + n) * Kpad + k;
      f16 h = (f16)v;
      dsth[o] = h;
      dstl[o] = (f16)(v - (float)h);
    }
  }
}

// ---- fused GEMM + gelu + LayerNorm, W-split f16 (2 MFMA), full-row tile -----
// BM=64, BN=512(=H), BK=64, 512 threads (8 waves: 2m x 4n), WM=32, WN=128.
// LDS 136KB: As 8K | Bh 64K | Bl 64K (dynamic). Staging = global_load_lds,
// linear dest + XOR-swizzled global source chunk, same XOR on ds_read (R6-proven).
// Epilogue: y = acc + bias (+ resid=A[m][n]); g = gelu(y); LN over n via
// cross-wave LDS reduction; out stored f16 ONCE (single act rounding/layer).
template<bool RES>
__global__ __launch_bounds__(512) void gemm_ln_kernel(
    const f16* __restrict__ A, const f16* __restrict__ Wh, const f16* __restrict__ Wl,
    const float* __restrict__ bias, const float* __restrict__ lns,
    const float* __restrict__ lnb, f16* __restrict__ out,
    int M, int Kd, int strideAS) {
  constexpr int BM = 64, BN = 512, BK = 64;
  constexpr int CPR = BK / 8, SWZ = CPR - 1;
  constexpr int WM = 32, WN = 128, FM = 2, FN = 8;
  extern __shared__ f16 smem[];
  f16* As  = smem;                 // 64*64
  f16* Bhs = As + BM * BK;         // 512*64
  f16* Bls = Bhs + BN * BK;        // 512*64

  const int s  = blockIdx.z;
  const int m0 = blockIdx.x * BM;
  const f16* ap  = A  + (size_t)s * strideAS + (size_t)m0 * Kd;
  const f16* wph = Wh + (size_t)s * BN * Kd;
  const f16* wpl = Wl + (size_t)s * BN * Kd;
  const int tid = threadIdx.x, wbase = tid & ~63;
  const int wave = tid >> 6, lane = tid & 63;
  const int wr = wave >> 2, wc = wave & 3;
  f32x4 acc[FM][FN] = {};
  const int laneRow = lane & 15;
  const int hi      = lane >> 4;

  for (int k0 = 0; k0 < Kd; k0 += BK) {
    __syncthreads();
    {   // A: 512 chunks, exactly 1/thread
      const int r = tid / CPR, c = tid % CPR, cg = c ^ (r & SWZ);
      gload16(ap + (size_t)r * Kd + k0 + cg * 8, As + (size_t)wbase * 8);
    }
#pragma unroll
    for (int base = 0; base < BN * CPR; base += 512) {  // B: 4096 chunks, 8/thread
      const int idx = base + tid;
      const int r = idx / CPR, c = idx % CPR, cg = c ^ (r & SWZ);
      const size_t go = (size_t)r * Kd + k0 + cg * 8;
      gload16(wph + go, Bhs + (size_t)(base + wbase) * 8);
      gload16(wpl + go, Bls + (size_t)(base + wbase) * 8);
    }
    __syncthreads();
#pragma unroll
    for (int kk = 0; kk < BK / 32; ++kk) {
      const int cc = kk * 4 + hi;
      f16x8 a[FM], bh[FN], bl[FN];
#pragma unroll
      for (int mi = 0; mi < FM; ++mi) {
        const int row = wr * WM + mi * 16 + laneRow;
        a[mi] = *reinterpret_cast<const f16x8*>(&As[row * BK + ((cc ^ (row & SWZ)) << 3)]);
      }
#pragma unroll
      for (int ni = 0; ni < FN; ++ni) {
        const int row = wc * WN + ni * 16 + laneRow;
        const int off = row * BK + ((cc ^ (row & SWZ)) << 3);
        bh[ni] = *reinterpret_cast<const f16x8*>(&Bhs[off]);
        bl[ni] = *reinterpret_cast<const f16x8*>(&Bls[off]);
      }
#pragma unroll
      for (int mi = 0; mi < FM; ++mi)
#pragma unroll
        for (int ni = 0; ni < FN; ++ni) {
          acc[mi][ni] = __builtin_amdgcn_mfma_f32_16x16x32_f16(a[mi], bh[ni], acc[mi][ni], 0, 0, 0);
          acc[mi][ni] = __builtin_amdgcn_mfma_f32_16x16x32_f16(a[mi], bl[ni], acc[mi][ni], 0, 0, 0);
        }
    }
  }

  // ---------------- fused epilogue: bias(+resid) -> gelu -> LN -> f16 -------
  const int rbase = hi * 4;
  float bv[FN], sv[FN], bb[FN];
#pragma unroll
  for (int ni = 0; ni < FN; ++ni) {
    const int gn = wc * WN + ni * 16 + laneRow;
    bv[ni] = bias[s * H + gn];
    sv[ni] = lns[s * H + gn];
    bb[ni] = lnb[s * H + gn];
  }
  float lsum[FM][4], lsq[FM][4];
#pragma unroll
  for (int mi = 0; mi < FM; ++mi)
#pragma unroll
    for (int r = 0; r < 4; ++r) { lsum[mi][r] = 0.f; lsq[mi][r] = 0.f; }
#pragma unroll
  for (int mi = 0; mi < FM; ++mi)
#pragma unroll
    for (int r = 0; r < 4; ++r) {
      const int row = wr * WM + mi * 16 + rbase + r;
#pragma unroll
      for (int ni = 0; ni < FN; ++ni) {
        const int gn = wc * WN + ni * 16 + laneRow;
        float y = acc[mi][ni][r] + bv[ni];
        if constexpr (RES)
          y += (float)A[(size_t)s * strideAS + (size_t)(m0 + row) * Kd + gn];
        float g = gelu_tanh(y);
        acc[mi][ni][r] = g;
        lsum[mi][r] += g;
        lsq[mi][r]  += g * g;
      }
    }
  // reduce across the 16 laneRow lanes (stay within 16-lane groups)
#pragma unroll
  for (int o = 1; o < 16; o <<= 1)
#pragma unroll
    for (int mi = 0; mi < FM; ++mi)
#pragma unroll
      for (int r = 0; r < 4; ++r) {
        lsum[mi][r] += __shfl_xor(lsum[mi][r], o, 64);
        lsq[mi][r]  += __shfl_xor(lsq[mi][r], o, 64);
      }
  __syncthreads();                       // all waves done reading As
  float* red = reinterpret_cast<float*>(smem);   // [64 rows][4 wc][2]
  if (laneRow == 0) {
#pragma unroll
    for (int mi = 0; mi < FM; ++mi)
#pragma unroll
      for (int r = 0; r < 4; ++r) {
        const int row = wr * WM + mi * 16 + rbase + r;
        red[(row * 4 + wc) * 2 + 0] = lsum[mi][r];
        red[(row * 4 + wc) * 2 + 1] = lsq[mi][r];
      }
  }
  __syncthreads();
#pragma unroll
  for (int mi = 0; mi < FM; ++mi)
#pragma unroll
    for (int r = 0; r < 4; ++r) {
      const int row = wr * WM + mi * 16 + rbase + r;
      float sum = 0.f, sq = 0.f;
#pragma unroll
      for (int w4 = 0; w4 < 4; ++w4) {
        sum += red[(row * 4 + w4) * 2 + 0];
        sq  += red[(row * 4 + w4) * 2 + 1];
      }
      const float mean = sum * (1.f / 512.f);
      const float var  = sq * (1.f / 512.f) - mean * mean;
      const float rstd = 1.f / sqrtf(var + 1e-6f);
#pragma unroll
      for (int ni = 0; ni < FN; ++ni) {
        const int gn = wc * WN + ni * 16 + laneRow;
        float z = (acc[mi][ni][r] - mean) * rstd * sv[ni] + bb[ni];
        out[((size_t)s * M + m0 + row) * H + gn] = (f16)z;
      }
    }
}

// ---- final projection GEMM, W-split f16 (2 MFMA), f32 out -------------------
// BM=64, BN=112, BK=64, 256 threads (4 waves: 4m x 1n), WM=16, WN=112.
__global__ __launch_bounds__(256) void gemm_out_kernel(
    const f16* __restrict__ A, const f16* __restrict__ Wh, const f16* __restrict__ Wl,
    const float* __restrict__ bias, float* __restrict__ out,
    int M, int Kd, int strideAS) {
  constexpr int BM = 64, BN = 112, BK = 64;
  constexpr int CPR = BK / 8, SWZ = CPR - 1;
  constexpr int FN = 7;
  extern __shared__ f16 smem[];
  f16* As  = smem;               // 64*64
  f16* Bhs = As + BM * BK;       // 112*64
  f16* Bls = Bhs + BN * BK;

  const int s  = blockIdx.z;
  const int m0 = blockIdx.x * BM;
  const f16* ap  = A  + (size_t)s * strideAS + (size_t)m0 * Kd;
  const f16* wph = Wh + (size_t)s * BN * Kd;
  const f16* wpl = Wl + (size_t)s * BN * Kd;
  const int tid = threadIdx.x, wbase = tid & ~63;
  const int wave = tid >> 6, lane = tid & 63;
  const int wr = wave;           // WM=16 rows per wave
  f32x4 acc[FN] = {};
  const int laneRow = lane & 15;
  const int hi      = lane >> 4;

  for (int k0 = 0; k0 < Kd; k0 += BK) {
    __syncthreads();
#pragma unroll
    for (int base = 0; base < BM * CPR; base += 256) {   // 512 chunks
      const int idx = base + tid;
      const int r = idx / CPR, c = idx % CPR, cg = c ^ (r & SWZ);
      gload16(ap + (size_t)r * Kd + k0 + cg * 8, As + (size_t)(base + wbase) * 8);
    }
#pragma unroll
    for (int base = 0; base < BN * CPR; base += 256) {   // 896 chunks, last partial
      const int idx = base + tid;
      if (idx < BN * CPR) {
        const int r = idx / CPR, c = idx % CPR, cg = c ^ (r & SWZ);
        const size_t go = (size_t)r * Kd + k0 + cg * 8;
        gload16(wph + go, Bhs + (size_t)(base + wbase) * 8);
        gload16(wpl + go, Bls + (size_t)(base + wbase) * 8);
      }
    }
    __syncthreads();
#pragma unroll
    for (int kk = 0; kk < BK / 32; ++kk) {
      const int cc = kk * 4 + hi;
      const int rowA = wr * 16 + laneRow;
      f16x8 a = *reinterpret_cast<const f16x8*>(&As[rowA * BK + ((cc ^ (rowA & SWZ)) << 3)]);
#pragma unroll
      for (int ni = 0; ni < FN; ++ni) {
        const int row = ni * 16 + laneRow;
        const int off = row * BK + ((cc ^ (row & SWZ)) << 3);
        f16x8 bh = *reinterpret_cast<const f16x8*>(&Bhs[off]);
        f16x8 bl = *reinterpret_cast<const f16x8*>(&Bls[off]);
        acc[ni] = __builtin_amdgcn_mfma_f32_16x16x32_f16(a, bh, acc[ni], 0, 0, 0);
        acc[ni] = __builtin_amdgcn_mfma_f32_16x16x32_f16(a, bl, acc[ni], 0, 0, 0);
      }
    }
  }

  const int rbase = hi * 4;
#pragma unroll
  for (int ni = 0; ni < FN; ++ni)
#pragma unroll
    for (int r = 0; r < 4; ++r) {
      const int gm = m0 + wr * 16 + rbase + r;
      const int gn = ni * 16 + laneRow;
      if (gn < OUTC)
        out[((size_t)s * M + gm) * OUTC + gn] = acc[ni][r] + bias[s * OUTC + gn];
    }
}

// ---------------- RQS spline: one thread per (b,i), params via LDS -----------
DI float invsymlu(float u) { return u >= 0.f ? u + 1.f : 1.f / (1.f - u); }

__global__ __launch_bounds__(128) void spline_kernel(
    const float* __restrict__ x, const float* __restrict__ bias0,
    const float* __restrict__ p, float* __restrict__ out0, float* __restrict__ ladbuf) {
  __shared__ float prm[128 * 101];   // stride 101: conflict-free
  const int i  = blockIdx.x;         // 0..15
  const int b0 = blockIdx.y * 128;
  if (i == 0) {
    for (int idx = threadIdx.x; idx < 128 * OUTC; idx += 128)
      prm[(idx / OUTC) * 101 + idx % OUTC] = bias0[idx % OUTC];
  } else {
    const float* src = p + ((size_t)(i - 1) * BATCH + b0) * OUTC;
    for (int idx = threadIdx.x; idx < 128 * OUTC; idx += 128)
      prm[(idx / OUTC) * 101 + idx % OUTC] = src[idx];
  }
  __syncthreads();
  const float* P = &prm[threadIdx.x * 101];
  const int b = b0 + threadIdx.x;
  const float inp = x[b * 16 + i];

  float tw = 0.f, th = 0.f;
  for (int k = 0; k < 32; ++k) tw += 0.001f + invsymlu(P[k]);
  for (int k = 0; k < 32; ++k) th += 0.001f + invsymlu(P[32 + k]);
  const float cx = P[97], cy = P[98];
  const float w0 = cx - 0.5f * tw, wK = cx + 0.5f * tw;
  const float h0 = cy - 0.5f * th, hK = cy + 0.5f * th;
  const float d0 = 0.001f + invsymlu(P[64]);
  const float dK = 0.001f + invsymlu(P[96]);
  float outv, lad;
  if (inp < w0) {
    outv = h0 - (w0 - inp) * d0;
    lad  = logf(d0);
  } else if (inp >= wK) {
    outv = (inp - wK) * dK + hK;
    lad  = logf(dK);
  } else {
    float run = w0, icw = w0, ibw = 1.f;
    int bin = 0;
    for (int k = 0; k < 32; ++k) {
      float wk = 0.001f + invsymlu(P[k]);
      if (inp >= run) { bin = k; icw = run; ibw = wk; }
      run += wk;
    }
    float runh = h0;
    for (int k = 0; k < bin; ++k) runh += 0.001f + invsymlu(P[32 + k]);
    const float ih    = 0.001f + invsymlu(P[32 + bin]);
    const float ich   = runh;
    const float ider  = 0.001f + invsymlu(P[64 + bin]);
    const float iderp = 0.001f + invsymlu(P[64 + bin + 1]);
    const float idl   = ih / ibw;
    const float theta = (inp - icw) / ibw;
    const float omt   = 1.f - theta;
    const float tomt  = theta * omt;
    const float num   = ih * (idl * theta * theta + ider * tomt);
    const float den   = idl + (ider + iderp - 2.f * idl) * tomt;
    outv = ich + num / den;
    const float dnum = idl * idl * (iderp * theta * theta + 2.f * idl * tomt + ider * omt * omt);
    lad = logf(dnum) - 2.f * logf(den);
  }
  out0[b * 16 + i]   = outv;
  ladbuf[b * 16 + i] = lad;
}

__global__ void lad_reduce_kernel(const float* __restrict__ ladbuf, float* __restrict__ out1) {
  const int b = blockIdx.x * 256 + threadIdx.x;
  float s = 0.f;
#pragma unroll
  for (int i = 0; i < 16; ++i) s += ladbuf[b * 16 + i];
  out1[b] = s;
}

// ---------------------------------------------------------------------------
extern "C" void kernel_launch(void* const* d_in, const int* in_sizes, int n_in,
                              void* d_out, int out_size, void* d_ws, size_t ws_size,
                              hipStream_t stream) {
  const float* x     = (const float*)d_in[0];
  const float* bias0 = (const float*)d_in[1];
  const float* W0    = (const float*)d_in[2];
  const float* b0    = (const float*)d_in[3];
  const float* ln0s  = (const float*)d_in[4];
  const float* ln0b  = (const float*)d_in[5];
  const float* W1    = (const float*)d_in[6];
  const float* b1    = (const float*)d_in[7];
  const float* ln1s  = (const float*)d_in[8];
  const float* ln1b  = (const float*)d_in[9];
  const float* W2    = (const float*)d_in[10];
  const float* b2    = (const float*)d_in[11];
  const float* ln2s  = (const float*)d_in[12];
  const float* ln2b  = (const float*)d_in[13];
  const float* Wf    = (const float*)d_in[14];
  const float* bfb   = (const float*)d_in[15];
  float* out0 = (float*)d_out;
  float* out1 = out0 + BATCH * 16;

  // ---- workspace budget ----------------------------------------------------
  const size_t fixedBytes =
      (size_t)BATCH * DPAD * 2 +                // e
      2 * ((size_t)S1 * H * DPAD * 2) +         // W0T h,l
      4 * ((size_t)S1 * H * H * 2) +            // W1T, W2T h,l
      2 * ((size_t)S1 * OUTPAD * H * 2) +       // WfT h,l
      (size_t)S1 * BATCH * OUTC * 4 +           // pbuf
      (size_t)BATCH * 16 * 4 +                  // ladb
      64 * 256;
  const size_t perSiteP = 2 * ((size_t)BATCH * H * 2);  // P1+P2 per site (single f16)
  int CH = 1;
  if (ws_size > fixedBytes) {
    size_t c = (ws_size - fixedBytes) / perSiteP;
    CH = (c >= (size_t)S1) ? S1 : (c < 1 ? 1 : (int)c);
  }
  const int nPasses = (S1 + CH - 1) / CH;
  const int baseSz  = S1 / nPasses;
  const int remSz   = S1 % nPasses;

  char* ws = (char*)d_ws;
  size_t off = 0;
  auto take = [&](size_t bytes) {
    char* q = ws + off;
    off += (bytes + 255) & ~(size_t)255;
    return q;
  };
  f16* e     = (f16*)take((size_t)BATCH * DPAD * 2);
  f16* W0Th  = (f16*)take((size_t)S1 * H * DPAD * 2);
  f16* W0Tl  = (f16*)take((size_t)S1 * H * DPAD * 2);
  f16* W1Th  = (f16*)take((size_t)S1 * H * H * 2);
  f16* W1Tl  = (f16*)take((size_t)S1 * H * H * 2);
  f16* W2Th  = (f16*)take((size_t)S1 * H * H * 2);
  f16* W2Tl  = (f16*)take((size_t)S1 * H * H * 2);
  f16* WfTh  = (f16*)take((size_t)S1 * OUTPAD * H * 2);
  f16* WfTl  = (f16*)take((size_t)S1 * OUTPAD * H * 2);
  f16* P1    = (f16*)take((size_t)CH * BATCH * H * 2);
  f16* P2    = (f16*)take((size_t)CH * BATCH * H * 2);
  float* pbuf = (float*)take((size_t)S1 * BATCH * OUTC * 4);
  float* ladb = (float*)take((size_t)BATCH * 16 * 4);

  embed_kernel<<<BATCH, 128, 0, stream>>>(x, e);
  transpose_conv_kernel<<<dim3(4, 16, S1), 256, 0, stream>>>(W0, W0Th, W0Tl, 120, H, DPAD, H, 8);
  transpose_conv_kernel<<<dim3(16, 16, S1), 256, 0, stream>>>(W1, W1Th, W1Tl, H, H, H, H, 0);
  transpose_conv_kernel<<<dim3(16, 16, S1), 256, 0, stream>>>(W2, W2Th, W2Tl, H, H, H, H, 0);
  transpose_conv_kernel<<<dim3(16, 4, S1), 256, 0, stream>>>(Wf, WfTh, WfTl, H, OUTC, H, OUTPAD, 0);

  const size_t ldsFused = (size_t)(64 + 512 + 512) * 64 * 2;  // 139264 B (<=160K/CU)
  const size_t ldsOut   = (size_t)(64 + 112 + 112) * 64 * 2;  // 36864 B

  int sb = 0;
  for (int pass = 0; pass < nPasses; ++pass) {
    const int nz = baseSz + (pass < remSz ? 1 : 0);
    // layer 0: e (shared) -> P2  [fused gelu+LN]
    gemm_ln_kernel<false><<<dim3(BATCH / 64, 1, nz), 512, ldsFused, stream>>>(
        e, W0Th + (size_t)sb * H * DPAD, W0Tl + (size_t)sb * H * DPAD,
        b0 + sb * H, ln0s + sb * H, ln0b + sb * H, P2, BATCH, DPAD, 0);
    // layer 1: P2 -> P1 (residual = P2)  [fused]
    gemm_ln_kernel<true><<<dim3(BATCH / 64, 1, nz), 512, ldsFused, stream>>>(
        P2, W1Th + (size_t)sb * H * H, W1Tl + (size_t)sb * H * H,
        b1 + sb * H, ln1s + sb * H, ln1b + sb * H, P1, BATCH, H, BATCH * H);
    // layer 2: P1 -> P2 (residual = P1)  [fused]
    gemm_ln_kernel<true><<<dim3(BATCH / 64, 1, nz), 512, ldsFused, stream>>>(
        P1, W2Th + (size_t)sb * H * H, W2Tl + (size_t)sb * H * H,
        b2 + sb * H, ln2s + sb * H, ln2b + sb * H, P2, BATCH, H, BATCH * H);
    // final projection: P2 -> pbuf (f32)
    gemm_out_kernel<<<dim3(BATCH / 64, 1, nz), 256, ldsOut, stream>>>(
        P2, WfTh + (size_t)sb * OUTPAD * H, WfTl + (size_t)sb * OUTPAD * H,
        bfb + sb * OUTC, pbuf + (size_t)sb * BATCH * OUTC, BATCH, H, BATCH * H);
    sb += nz;
  }

  spline_kernel<<<dim3(16, 32), 128, 0, stream>>>(x, bias0, pbuf, out0, ladb);
  lad_reduce_kernel<<<BATCH / 256, 256, 0, stream>>>(ladb, out1);
}